// Round 13
// baseline (308.676 us; speedup 1.0000x reference)
//
#include <hip/hip_runtime.h>
#include <cstdint>
#include <cstddef>

#define DM   1024
#define DI   2048
#define SEQ  2048
#define NB   4
#define NTOK (NB*SEQ)   // 8192
#define CCH  32          // scan chunks per sequence
#define LC   (SEQ/CCH)   // 64 timesteps per chunk
#define KS   8           // K-split for xp_gemm

typedef __attribute__((ext_vector_type(8))) short short8v;
typedef __attribute__((ext_vector_type(4))) float f32x4;
typedef unsigned short u16;
typedef unsigned int   u32;

__device__ __forceinline__ float silu_f(float x){ return x / (1.f + __expf(-x)); }

// cheap softplus: inline v_exp + v_log (log1pf is a slow libm path — r7 lesson)
__device__ __forceinline__ float softplus_f(float x){
  return (x > 20.f) ? x : __logf(1.f + __expf(x));
}

__device__ __forceinline__ u16 f2bf(float f){
  union { float f; u32 u; } c; c.f = f;
  u32 u = c.u + 0x7FFFu + ((c.u >> 16) & 1u);   // RNE
  return (u16)(u >> 16);
}
__device__ __forceinline__ float b2f(u16 b){
  union { u32 u; float f; } c; c.u = ((u32)b) << 16; return c.f;
}
__device__ __forceinline__ float lo2f(u32 v){ union { u32 u; float f; } c; c.u = v << 16; return c.f; }
__device__ __forceinline__ float hi2f(u32 v){ union { u32 u; float f; } c; c.u = v & 0xFFFF0000u; return c.f; }
__device__ __forceinline__ u32 pack2(float a, float b){ return (u32)f2bf(a) | ((u32)f2bf(b) << 16); }

__device__ __forceinline__ void gl16(const void* g, void* l){
  __builtin_amdgcn_global_load_lds((const __attribute__((address_space(1))) void*)g,
                                   (__attribute__((address_space(3))) void*)l, 16, 0, 0);
}

// ---------------- fp32 -> bf16 bulk convert --------------------------------
__global__ __launch_bounds__(256) void cvtk(const float4* __restrict__ in,
                                            u16* __restrict__ outp, int n4)
{
  int i = blockIdx.x * 256 + threadIdx.x;
  if (i < n4) {
    float4 v = in[i];
    *(uint2*)(outp + (size_t)i * 4) = make_uint2(pack2(v.x, v.y), pack2(v.z, v.w));
  }
}

// ---------------- fp32 [R][Cn] -> bf16 [Cn][R] transpose-convert -----------
__global__ __launch_bounds__(256) void transcvt(
    const float* __restrict__ W, u16* __restrict__ Wt, int R, int Cn)
{
  __shared__ float t[64][65];
  const int tid = threadIdx.x;
  const int bx = blockIdx.x, by = blockIdx.y;
  const int lr4 = tid >> 6;   // 0..3
  const int lc  = tid & 63;
  #pragma unroll
  for (int p = 0; p < 16; ++p) {
    int lr = p * 4 + lr4;
    t[lr][lc] = W[(size_t)(by * 64 + lr) * Cn + bx * 64 + lc];
  }
  __syncthreads();
  #pragma unroll
  for (int p = 0; p < 16; ++p) {
    int orr = p * 4 + lr4;
    Wt[(size_t)(bx * 64 + orr) * R + by * 64 + lc] = f2bf(t[lc][orr]);
  }
}

// ---------------- small-weight prep ----------------------------------------
__global__ __launch_bounds__(256) void prep_smallw(
    const float* __restrict__ W_x, const float* __restrict__ W_dt,
    const float* __restrict__ W_Bp, u16* __restrict__ Wxt, u16* __restrict__ Wbig)
{
  int i = blockIdx.x * 256 + threadIdx.x;
  if (i < 32 * DI) {
    int j = i >> 11, c = i & (DI - 1);
    Wxt[i] = f2bf(W_x[c * 32 + j]);
  }
  int i2 = i - 32 * DI;
  if (i2 >= 0 && i2 < 2 * DI * 32) {
    int n = i2 >> 5, k = i2 & 31;
    float v;
    if (n < DI) v = (k < 16) ? W_dt[k * DI + n] : 0.f;
    else        v = (k >= 16) ? W_Bp[(k - 16) * DI + (n - DI)] : 0.f;
    Wbig[i2] = f2bf(v);
  }
}

// ---------------- 3-resident-block pipelined MFMA GEMM ---------------------
// A [M][K] bf16, Bt [N][K] bf16. BM=BN=128, BK=32, 256 thr (2x2 waves,
// 64x64/wave). 2-deep LDS dbuf = 32 KiB -> 3 blocks/CU (r13: occupancy is
// the lever; r11 showed cross-block TLP is what hides vmcnt/barrier
// stalls). Counted vmcnt(4): tile t+2 issued after compute(t) (T4). XOR
// swizzle re-derived for 64B rows: slot ^= (row>>1)&3 so (row&1,slot)
// spans 8 combos per 16-lane group -> 2-way = free (G4). Pre-swizzled
// GLOBAL source + swizzled ds_read (rule #21). No XCD swizzle (r12: it
// raised FETCH 82->139 MB and cost 4 us — reverted).
template<int NT, int OBF16>
__global__ __launch_bounds__(256, 3) void gemm2b(
    const u16* __restrict__ A, const u16* __restrict__ Bt,
    void* C0v, void* C1v, int K, int split, int ldc)
{
  __shared__ __align__(16) u16 Ab[2][128 * 32];   // 2 x 8 KiB
  __shared__ __align__(16) u16 Bb[2][128 * 32];   // 2 x 8 KiB
  const int tid = threadIdx.x, lane = tid & 63, w = tid >> 6;
  const int wm = w >> 1, wn = w & 1;
  const int bm = blockIdx.y * 128, bn = blockIdx.x * 128;

  // staging: per gl16-issue 256 thr x 16B = 64 rows x 64B; 2 issues per
  // operand tile. thread -> row tid>>2 (0..63), slot tid&3; slot XOR-
  // swizzled with (row>>1)&3 on the GLOBAL side, LDS dest linear.
  const int srow = tid >> 2;                      // 0..63
  const int kc = ((tid & 3) ^ ((srow >> 1) & 3)) << 3;   // swizzled u16 col
  const u16* Ag = A  + (size_t)(bm + srow) * K + kc;
  const u16* Bg = Bt + (size_t)(bn + srow) * K + kc;

  // fragment-read constants (inverse swizzle on LDS side):
  // row = base + i*16 + l15; (row>>1)&3 == (l15>>1)&3 (base multiples of 16)
  const int lq = lane >> 4, l15 = lane & 15;
  const int co = ((lq ^ ((l15 >> 1) & 3)) << 3);  // swizzled k-slot (u16)
  const int abase = (wm * 64 + l15) * 32;
  const int bbase = (wn * 64 + l15) * 32;

  f32x4 acc[4][4] = {};

  auto issue = [&](int t, int buf) {
    const size_t k0 = (size_t)t << 5;
    gl16(Ag + k0,                    &Ab[buf][tid * 8]);          // rows 0-63
    gl16(Ag + (size_t)64 * K + k0,   &Ab[buf][2048 + tid * 8]);   // rows 64-127
    gl16(Bg + k0,                    &Bb[buf][tid * 8]);
    gl16(Bg + (size_t)64 * K + k0,   &Bb[buf][2048 + tid * 8]);
  };
  auto compute = [&](int buf) {
    const u16* Ac = Ab[buf];
    const u16* Bc = Bb[buf];
    short8v af[4], bf[4];
    #pragma unroll
    for (int i = 0; i < 4; ++i) af[i] = *(const short8v*)&Ac[abase + i * 512 + co];
    #pragma unroll
    for (int j = 0; j < 4; ++j) bf[j] = *(const short8v*)&Bc[bbase + j * 512 + co];
    __builtin_amdgcn_s_setprio(1);
    #pragma unroll
    for (int i = 0; i < 4; ++i)
      #pragma unroll
      for (int j = 0; j < 4; ++j)
        acc[i][j] = __builtin_amdgcn_mfma_f32_16x16x32_bf16(af[i], bf[j], acc[i][j], 0, 0, 0);
    __builtin_amdgcn_s_setprio(0);
  };

  // prologue: 2 tiles in flight (8 gl16)
  issue(0, 0); issue(1, 1);
  #pragma unroll 1
  for (int t = 0; t < NT; ++t) {
    if (t + 1 < NT) asm volatile("s_waitcnt vmcnt(4)" ::: "memory");  // tile t landed
    else            asm volatile("s_waitcnt vmcnt(0)" ::: "memory");
    __builtin_amdgcn_s_barrier(); __builtin_amdgcn_sched_barrier(0);
    compute(t & 1);
    __builtin_amdgcn_s_barrier(); __builtin_amdgcn_sched_barrier(0);
    if (t + 2 < NT) issue(t + 2, t & 1);            // reuse buf just read
  }

  // epilogue: C row = (lane>>4)*4 + r, col = lane&15 (m89 mapping)
  const bool left = (bn < split);
  const int cb = bn - (left ? 0 : split) + wn * 64 + l15;
  const int rb = bm + wm * 64 + lq * 4;
  if (OBF16) {
    u16* Cp = (u16*)(left ? C0v : C1v);
    #pragma unroll
    for (int i = 0; i < 4; ++i)
      #pragma unroll
      for (int j = 0; j < 4; ++j)
        #pragma unroll
        for (int r = 0; r < 4; ++r)
          Cp[(size_t)(rb + i * 16 + r) * ldc + cb + j * 16] = f2bf(acc[i][j][r]);
  } else {
    float* Cp = (float*)(left ? C0v : C1v);
    #pragma unroll
    for (int i = 0; i < 4; ++i)
      #pragma unroll
      for (int j = 0; j < 4; ++j)
        #pragma unroll
        for (int r = 0; r < 4; ++r)
          Cp[(size_t)(rb + i * 16 + r) * ldc + cb + j * 16] = acc[i][j][r];
  }
}

// ---------------- skinny GEMM: xp_part[gy] = u @ W_x (K-slice) -------------
__global__ __launch_bounds__(256) void xp_gemm(
    const u16* __restrict__ A, const u16* __restrict__ Bt, float* __restrict__ xpp)
{
  __shared__ __align__(16) u16 Asm[128 * 32];
  __shared__ __align__(16) u16 Bsm[32 * 32];
  const int tid = threadIdx.x, lane = tid & 63, w = tid >> 6;
  const int bm = blockIdx.x * 128;
  const int kbase = blockIdx.y * (DI / KS);
  f32x4 acc[2][2] = {};
  const int srow = w * 32 + (lane >> 2);
  const int soct = lane & 3;
  const u16* Ap = A + (size_t)(bm + srow) * DI + kbase + soct * 8;
  const u16* Bp = Bt + (size_t)(lane >> 2) * DI + kbase + soct * 8;
  u16* As0 = &Asm[w * 1024];

  for (int k0 = 0; k0 < DI / KS; k0 += 32) {
    gl16(Ap + k0,                      As0);
    gl16(Ap + k0 + (size_t)16 * DI,    As0 + 512);
    if (w == 0) {
      gl16(Bp + k0,                    Bsm);
      gl16(Bp + k0 + (size_t)16 * DI,  Bsm + 512);
    }
    __syncthreads();
    short8v af[2], bf[2];
    #pragma unroll
    for (int i = 0; i < 2; ++i)
      af[i] = *(const short8v*)&Asm[(w * 32 + i * 16 + (lane & 15)) * 32 + (lane >> 4) * 8];
    #pragma unroll
    for (int j = 0; j < 2; ++j)
      bf[j] = *(const short8v*)&Bsm[(j * 16 + (lane & 15)) * 32 + (lane >> 4) * 8];
    #pragma unroll
    for (int i = 0; i < 2; ++i)
      #pragma unroll
      for (int j = 0; j < 2; ++j)
        acc[i][j] = __builtin_amdgcn_mfma_f32_16x16x32_bf16(af[i], bf[j], acc[i][j], 0, 0, 0);
    __syncthreads();
  }
  float* op = xpp + (size_t)blockIdx.y * NTOK * 32;
  const int rb = bm + w * 32 + (lane >> 4) * 4;
  const int cb = lane & 15;
  #pragma unroll
  for (int i = 0; i < 2; ++i)
    #pragma unroll
    for (int j = 0; j < 2; ++j)
      #pragma unroll
      for (int r = 0; r < 4; ++r)
        op[(size_t)(rb + i * 16 + r) * 32 + cb + j * 16] = acc[i][j][r];
}

// ---------------- reduce KS partials -> xp bf16 ----------------------------
__global__ __launch_bounds__(256) void xp_reduce(
    const float* __restrict__ xpp, u16* __restrict__ xpb)
{
  int i = blockIdx.x * 256 + threadIdx.x;   // over NTOK*32
  float s = 0.f;
  #pragma unroll
  for (int k = 0; k < KS; ++k) s += xpp[(size_t)k * NTOK * 32 + i];
  xpb[i] = f2bf(s);
}

// ---------------- dt/ub GEMM: [xp][Wbig] K=32, fused epilogue --------------
__global__ __launch_bounds__(256) void dtub_gemm(
    const u16* __restrict__ A, const u16* __restrict__ Bt,
    const float* __restrict__ b_dt, const u16* __restrict__ u,
    u16* __restrict__ dt_out, u16* __restrict__ ub_out)
{
  __shared__ __align__(16) u16 Asm[128 * 32];
  __shared__ __align__(16) u16 Bsm[128 * 32];
  const int tid = threadIdx.x, lane = tid & 63, w = tid >> 6;
  const int wm = w >> 1, wn = w & 1;
  const int bm = blockIdx.y * 128, bn = blockIdx.x * 128;
  const int srow = w * 32 + (lane >> 2);
  const int soct = lane & 3;
  u16* As0 = &Asm[w * 1024];
  u16* Bs0 = &Bsm[w * 1024];
  gl16(A  + (size_t)(bm + srow) * 32 + soct * 8,       As0);
  gl16(A  + (size_t)(bm + srow) * 32 + soct * 8 + 512, As0 + 512);
  gl16(Bt + (size_t)(bn + srow) * 32 + soct * 8,       Bs0);
  gl16(Bt + (size_t)(bn + srow) * 32 + soct * 8 + 512, Bs0 + 512);
  __syncthreads();
  f32x4 acc[4][4] = {};
  short8v afr[4], bfr[4];
  #pragma unroll
  for (int i = 0; i < 4; ++i) {
    afr[i] = *(const short8v*)&Asm[(wm * 64 + i * 16 + (lane & 15)) * 32 + (lane >> 4) * 8];
    bfr[i] = *(const short8v*)&Bsm[(wn * 64 + i * 16 + (lane & 15)) * 32 + (lane >> 4) * 8];
  }
  #pragma unroll
  for (int i = 0; i < 4; ++i)
    #pragma unroll
    for (int j = 0; j < 4; ++j)
      acc[i][j] = __builtin_amdgcn_mfma_f32_16x16x32_bf16(afr[i], bfr[j], acc[i][j], 0, 0, 0);

  const int rb = bm + wm * 64 + (lane >> 4) * 4;
  const int cb = bn + wn * 64 + (lane & 15);
  if (bn < DI) {          // dt half
    float bd[4];
    #pragma unroll
    for (int j = 0; j < 4; ++j) bd[j] = b_dt[cb + j * 16];
    #pragma unroll
    for (int i = 0; i < 4; ++i)
      #pragma unroll
      for (int j = 0; j < 4; ++j)
        #pragma unroll
        for (int r = 0; r < 4; ++r) {
          float sp = softplus_f(acc[i][j][r] + bd[j]);
          sp = fminf(fmaxf(sp, 1e-4f), 1.0f);
          dt_out[(size_t)(rb + i * 16 + r) * DI + cb + j * 16] = f2bf(sp);
        }
  } else {                // ub half
    const int cn = cb - DI;
    #pragma unroll
    for (int i = 0; i < 4; ++i)
      #pragma unroll
      for (int j = 0; j < 4; ++j)
        #pragma unroll
        for (int r = 0; r < 4; ++r) {
          size_t off = (size_t)(rb + i * 16 + r) * DI + cn + j * 16;
          ub_out[off] = f2bf(b2f(u[off]) * acc[i][j][r]);
        }
  }
}

// ------- causal depthwise conv(4) + silu, bf16 io, 4 ch/thread -------------
__global__ __launch_bounds__(256) void conv_silu_k(
    const u16* __restrict__ xc, const float* __restrict__ cw, u16* __restrict__ u)
{
  int idx = blockIdx.x * 256 + threadIdx.x;   // over NTOK*DI/4
  int c = (idx & (DI / 4 - 1)) << 2;
  int r = idx >> 9;
  int t = r & (SEQ - 1);
  float4 w0 = ((const float4*)cw)[c + 0];
  float4 w1 = ((const float4*)cw)[c + 1];
  float4 w2 = ((const float4*)cw)[c + 2];
  float4 w3 = ((const float4*)cw)[c + 3];
  const u16* base = xc + (size_t)r * DI + c;
  uint2 v = *(const uint2*)base;
  float a0 = w0.w * lo2f(v.x), a1 = w1.w * hi2f(v.x);
  float a2 = w2.w * lo2f(v.y), a3 = w3.w * hi2f(v.y);
  if (t >= 1) { v = *(const uint2*)(base - DI);
    a0 += w0.z * lo2f(v.x); a1 += w1.z * hi2f(v.x); a2 += w2.z * lo2f(v.y); a3 += w3.z * hi2f(v.y); }
  if (t >= 2) { v = *(const uint2*)(base - 2 * DI);
    a0 += w0.y * lo2f(v.x); a1 += w1.y * hi2f(v.x); a2 += w2.y * lo2f(v.y); a3 += w3.y * hi2f(v.y); }
  if (t >= 3) { v = *(const uint2*)(base - 3 * DI);
    a0 += w0.x * lo2f(v.x); a1 += w1.x * hi2f(v.x); a2 += w2.x * lo2f(v.y); a3 += w3.x * hi2f(v.y); }
  *(uint2*)(u + (size_t)r * DI + c) =
      make_uint2(pack2(silu_f(a0), silu_f(a1)), pack2(silu_f(a2), silu_f(a3)));
}

// ---------------- chunked parallel scan (bf16 in, 4 ch/thread) -------------
__global__ __launch_bounds__(256) void scan_p1(
    const u16* __restrict__ dt_, const u16* __restrict__ ub,
    float* __restrict__ P, float* __restrict__ S)
{
  int idx = blockIdx.x * 256 + threadIdx.x;   // NB*CCH*DI/4
  int di = (idx & (DI / 4 - 1)) << 2;
  int bc = idx >> 9;
  int c  = bc & (CCH - 1);
  int b  = bc >> 5;
  size_t base = ((size_t)b * SEQ + (size_t)c * LC) * DI + di;
  float p0 = 1.f, s0 = 0.f, p1 = 1.f, s1 = 0.f;
  float p2 = 1.f, s2 = 0.f, p3 = 1.f, s3 = 0.f;
  #pragma unroll 4
  for (int t = 0; t < LC; ++t) {
    size_t off = base + (size_t)t * DI;
    uint2 dv = *(const uint2*)(dt_ + off);
    uint2 uv = *(const uint2*)(ub + off);
    float a0 = 1.f - lo2f(dv.x), a1 = 1.f - hi2f(dv.x);
    float a2 = 1.f - lo2f(dv.y), a3 = 1.f - hi2f(dv.y);
    s0 = s0 * a0 + lo2f(uv.x); p0 *= a0;
    s1 = s1 * a1 + hi2f(uv.x); p1 *= a1;
    s2 = s2 * a2 + lo2f(uv.y); p2 *= a2;
    s3 = s3 * a3 + hi2f(uv.y); p3 *= a3;
  }
  ((float4*)P)[idx] = make_float4(p0, p1, p2, p3);
  ((float4*)S)[idx] = make_float4(s0, s1, s2, s3);
}

__global__ __launch_bounds__(256) void scan_p2(
    const float* __restrict__ P, const float* __restrict__ S, float* __restrict__ Hin)
{
  int idx = blockIdx.x * 256 + threadIdx.x;   // NB*DI
  int di = idx & (DI - 1);
  int b  = idx >> 11;
  float h = 0.f;
  #pragma unroll
  for (int c = 0; c < CCH; ++c) {
    size_t off = ((size_t)b * CCH + c) * DI + di;
    Hin[off] = h;
    h = h * P[off] + S[off];
  }
}

// y bf16 in-place over dt (same-index read-before-write) — no __restrict__.
__global__ __launch_bounds__(256) void scan_p3(
    const u16* dt_, const u16* __restrict__ ub, const u16* __restrict__ u,
    const u16* __restrict__ z, const float* __restrict__ Dp_,
    const float* __restrict__ Hin, u16* y)
{
  int idx = blockIdx.x * 256 + threadIdx.x;   // NB*CCH*DI/4
  int di = (idx & (DI / 4 - 1)) << 2;
  int bc = idx >> 9;
  int c  = bc & (CCH - 1);
  int b  = bc >> 5;
  float4 dp = ((const float4*)Dp_)[di >> 2];
  float4 h4 = ((const float4*)Hin)[idx];
  float h0 = h4.x, h1 = h4.y, h2 = h4.z, h3 = h4.w;
  size_t base = ((size_t)b * SEQ + (size_t)c * LC) * DI + di;
  #pragma unroll 4
  for (int t = 0; t < LC; ++t) {
    size_t off = base + (size_t)t * DI;
    uint2 dv = *(const uint2*)(dt_ + off);
    uint2 uv = *(const uint2*)(ub + off);
    uint2 uu = *(const uint2*)(u + off);
    uint2 zv = *(const uint2*)(z + off);
    h0 = h0 * (1.f - lo2f(dv.x)) + lo2f(uv.x);
    h1 = h1 * (1.f - hi2f(dv.x)) + hi2f(uv.x);
    h2 = h2 * (1.f - lo2f(dv.y)) + lo2f(uv.y);
    h3 = h3 * (1.f - hi2f(dv.y)) + hi2f(uv.y);
    float y0 = (h0 + dp.x * lo2f(uu.x)) * silu_f(lo2f(zv.x));
    float y1 = (h1 + dp.y * hi2f(uu.x)) * silu_f(hi2f(zv.x));
    float y2 = (h2 + dp.z * lo2f(uu.y)) * silu_f(lo2f(zv.y));
    float y3 = (h3 + dp.w * hi2f(uu.y)) * silu_f(hi2f(zv.y));
    *(uint2*)(y + off) = make_uint2(pack2(y0, y1), pack2(y2, y3));
  }
}

extern "C" void kernel_launch(void* const* d_in, const int* in_sizes, int n_in,
                              void* d_out, int out_size, void* d_ws, size_t ws_size,
                              hipStream_t stream)
{
  const float* x     = (const float*)d_in[0];
  const float* W_in  = (const float*)d_in[1];
  const float* cw    = (const float*)d_in[2];
  const float* W_x   = (const float*)d_in[3];
  const float* W_dt  = (const float*)d_in[4];
  const float* b_dt  = (const float*)d_in[5];
  const float* W_Bp  = (const float*)d_in[6];
  const float* Dp    = (const float*)d_in[7];
  const float* W_out = (const float*)d_in[8];
  float* out = (float*)d_out;

  const size_t SZ = (size_t)NTOK * DI;        // floats per ws region
  float* w    = (float*)d_ws;
  float* bufA = w;
  float* bufB = w + SZ;
  float* bufC = w + 2 * SZ;
  float* bufD = w + 3 * SZ;

  u16* xcb  = (u16*)bufA;                     // xc bf16 -> dt bf16 -> y bf16
  u16* zb   = (u16*)bufB;                     // z bf16 [NTOK][DI]
  u16* wtob = zb + (size_t)NTOK * DI;         // Wt_out bf16 [DM][DI]
  u16* wxt  = wtob + (size_t)DM * DI;         // Wxt bf16 [32][DI]
  u16* wbig = wxt + (size_t)32 * DI;          // Wbig bf16 [4096][32]
  u16* xbf  = (u16*)bufC;                     // x bf16 [NTOK][DM]
  u16* wtib = xbf + (size_t)NTOK * DM;        // Wt_in bf16 [2DI][DM]
  u16* ubf  = (u16*)bufC;                     // u bf16 (over dead xbf/wtib)
  u16* ubb  = (u16*)bufD;                     // ub bf16

  const size_t PS = (size_t)NB * CCH * DI;    // 262144 floats
  float* Pbuf   = out;                        // scan + xp scratch in d_out
  float* Sbuf   = out + PS;                   // (GEMM2 rewrites d_out fully)
  float* Hin    = out + 2 * PS;
  float* xppart = out + 3 * PS;               // [KS][NTOK][32] fp32 (8 MB)
  u16*   xpb    = (u16*)(out + 3 * PS + (size_t)KS * NTOK * 32);
  (void)ws_size; (void)in_sizes; (void)n_in; (void)out_size;

  // 0) one-shot conversions / weight prep
  cvtk<<<(NTOK * DM / 4) / 256, 256, 0, stream>>>((const float4*)x, xbf, NTOK * DM / 4);
  transcvt<<<dim3((2 * DI) / 64, DM / 64), 256, 0, stream>>>(W_in, wtib, DM, 2 * DI);
  transcvt<<<dim3(DM / 64, DI / 64), 256, 0, stream>>>(W_out, wtob, DI, DM);
  prep_smallw<<<(32 * DI + 2 * DI * 32) / 256, 256, 0, stream>>>(W_x, W_dt, W_Bp, wxt, wbig);

  // 1) xz = x @ W_in -> xc (bf16, bufA), z (bf16, bufB)  [3-resident, BK=32]
  gemm2b<DM / 32, 1><<<dim3((2 * DI) / 128, NTOK / 128), 256, 0, stream>>>(
      xbf, wtib, (void*)xcb, (void*)zb, DM, DI, DI);

  // 2) u = silu(causal depthwise conv(xc))
  conv_silu_k<<<(NTOK * DI / 4) / 256, 256, 0, stream>>>(xcb, cw, ubf);

  // 3) xp = u @ W_x (K-split MFMA + reduce), then dt/ub via K=32 MFMA
  xp_gemm<<<dim3(NTOK / 128, KS), 256, 0, stream>>>(ubf, wxt, xppart);
  xp_reduce<<<(NTOK * 32) / 256, 256, 0, stream>>>(xppart, xpb);
  dtub_gemm<<<dim3((2 * DI) / 128, NTOK / 128), 256, 0, stream>>>(
      xpb, wbig, b_dt, ubf, xcb, ubb);

  // 4) chunked scan + epilogue -> y bf16 (in place over dt)
  scan_p1<<<(NB * CCH * DI / 4) / 256, 256, 0, stream>>>(xcb, ubb, Pbuf, Sbuf);
  scan_p2<<<(NB * DI) / 256, 256, 0, stream>>>(Pbuf, Sbuf, Hin);
  scan_p3<<<(NB * CCH * DI / 4) / 256, 256, 0, stream>>>(xcb, ubb, ubf, zb, Dp, Hin, xcb);

  // 5) out = y @ W_out (fp32 out)  [3-resident, BK=32]
  gemm2b<DI / 32, 0><<<dim3(DM / 128, NTOK / 128), 256, 0, stream>>>(
      xcb, wtob, (void*)out, (void*)out, DI, DM, DM);
}

// Round 14
// 308.156 us; speedup vs baseline: 1.0017x; 1.0017x over previous
//
#include <hip/hip_runtime.h>
#include <cstdint>
#include <cstddef>

#define DM   1024
#define DI   2048
#define SEQ  2048
#define NB   4
#define NTOK (NB*SEQ)   // 8192
#define CCH  32          // scan chunks per sequence
#define LC   (SEQ/CCH)   // 64 timesteps per chunk
#define KS   8           // K-split for xp_gemm

typedef __attribute__((ext_vector_type(8))) short short8v;
typedef __attribute__((ext_vector_type(4))) float f32x4;
typedef unsigned short u16;
typedef unsigned int   u32;

__device__ __forceinline__ float silu_f(float x){ return x / (1.f + __expf(-x)); }

// cheap softplus: inline v_exp + v_log (log1pf is a slow libm path — r7 lesson)
__device__ __forceinline__ float softplus_f(float x){
  return (x > 20.f) ? x : __logf(1.f + __expf(x));
}

__device__ __forceinline__ u16 f2bf(float f){
  union { float f; u32 u; } c; c.f = f;
  u32 u = c.u + 0x7FFFu + ((c.u >> 16) & 1u);   // RNE
  return (u16)(u >> 16);
}
__device__ __forceinline__ float b2f(u16 b){
  union { u32 u; float f; } c; c.u = ((u32)b) << 16; return c.f;
}
__device__ __forceinline__ float lo2f(u32 v){ union { u32 u; float f; } c; c.u = v << 16; return c.f; }
__device__ __forceinline__ float hi2f(u32 v){ union { u32 u; float f; } c; c.u = v & 0xFFFF0000u; return c.f; }
__device__ __forceinline__ u32 pack2(float a, float b){ return (u32)f2bf(a) | ((u32)f2bf(b) << 16); }

__device__ __forceinline__ void gl16(const void* g, void* l){
  __builtin_amdgcn_global_load_lds((const __attribute__((address_space(1))) void*)g,
                                   (__attribute__((address_space(3))) void*)l, 16, 0, 0);
}

// ---------------- fp32 -> bf16 bulk convert --------------------------------
__global__ __launch_bounds__(256) void cvtk(const float4* __restrict__ in,
                                            u16* __restrict__ outp, int n4)
{
  int i = blockIdx.x * 256 + threadIdx.x;
  if (i < n4) {
    float4 v = in[i];
    *(uint2*)(outp + (size_t)i * 4) = make_uint2(pack2(v.x, v.y), pack2(v.z, v.w));
  }
}

// ---------------- fp32 [R][Cn] -> bf16 [Cn][R] transpose-convert -----------
__global__ __launch_bounds__(256) void transcvt(
    const float* __restrict__ W, u16* __restrict__ Wt, int R, int Cn)
{
  __shared__ float t[64][65];
  const int tid = threadIdx.x;
  const int bx = blockIdx.x, by = blockIdx.y;
  const int lr4 = tid >> 6;   // 0..3
  const int lc  = tid & 63;
  #pragma unroll
  for (int p = 0; p < 16; ++p) {
    int lr = p * 4 + lr4;
    t[lr][lc] = W[(size_t)(by * 64 + lr) * Cn + bx * 64 + lc];
  }
  __syncthreads();
  #pragma unroll
  for (int p = 0; p < 16; ++p) {
    int orr = p * 4 + lr4;
    Wt[(size_t)(bx * 64 + orr) * R + by * 64 + lc] = f2bf(t[lc][orr]);
  }
}

// ---------------- small-weight prep ----------------------------------------
__global__ __launch_bounds__(256) void prep_smallw(
    const float* __restrict__ W_x, const float* __restrict__ W_dt,
    const float* __restrict__ W_Bp, u16* __restrict__ Wxt, u16* __restrict__ Wbig)
{
  int i = blockIdx.x * 256 + threadIdx.x;
  if (i < 32 * DI) {
    int j = i >> 11, c = i & (DI - 1);
    Wxt[i] = f2bf(W_x[c * 32 + j]);
  }
  int i2 = i - 32 * DI;
  if (i2 >= 0 && i2 < 2 * DI * 32) {
    int n = i2 >> 5, k = i2 & 31;
    float v;
    if (n < DI) v = (k < 16) ? W_dt[k * DI + n] : 0.f;
    else        v = (k >= 16) ? W_Bp[(k - 16) * DI + (n - DI)] : 0.f;
    Wbig[i2] = f2bf(v);
  }
}

// ---------------- 2-resident-block pipelined MFMA GEMM (r11 config) --------
// A [M][K] bf16, Bt [N][K] bf16. BM=BN=128, BK=64, 256 thr (2x2 waves,
// 64x64/wave). 2-deep LDS dbuf = 64 KiB -> 2 blocks/CU (r11: cross-block
// TLP is what hides vmcnt/barrier stalls; r12 XCD-swizzle and r13 BK=32/
// 3-resident both regressed vs this — measured local optimum ~810 TF).
// Counted vmcnt(8) (T4), XOR swizzle via pre-swizzled global source
// (rule #21, conflicts=0), setprio (T5).
template<int NT, int OBF16>
__global__ __launch_bounds__(256, 2) void gemm2b(
    const u16* __restrict__ A, const u16* __restrict__ Bt,
    void* C0v, void* C1v, int K, int split, int ldc)
{
  __shared__ __align__(16) u16 Ab[2][128 * 64];   // 2 x 16 KiB
  __shared__ __align__(16) u16 Bb[2][128 * 64];   // 2 x 16 KiB
  const int tid = threadIdx.x, lane = tid & 63, w = tid >> 6;
  const int wm = w >> 1, wn = w & 1;
  const int bm = blockIdx.y * 128, bn = blockIdx.x * 128;

  // staging: per gl16-issue 256 thr x 16B = 32 rows x 128B; 4 issues per
  // operand tile. XOR-swizzled on the GLOBAL side, LDS dest linear.
  const int srow8 = tid >> 3;                     // 0..31
  const int kc = ((tid & 7) ^ (srow8 & 7)) << 3;  // swizzled u16 col
  const u16* Ag = A  + (size_t)(bm + srow8) * K + kc;
  const u16* Bg = Bt + (size_t)(bn + srow8) * K + kc;

  // fragment-read constants (inverse swizzle on LDS side)
  const int lq = lane >> 4, l15 = lane & 15;
  const int co0 = ((lq    ) ^ (l15 & 7)) << 3;    // ks=0 col (u16)
  const int co1 = ((lq + 4) ^ (l15 & 7)) << 3;    // ks=1
  const int abase = (wm * 64 + l15) * 64;
  const int bbase = (wn * 64 + l15) * 64;

  f32x4 acc[4][4] = {};

  auto issue = [&](int t, int buf) {
    const size_t k0 = (size_t)t << 6;
    #pragma unroll
    for (int q = 0; q < 4; ++q)
      gl16(Ag + (size_t)(q * 32) * K + k0, &Ab[buf][q * 2048 + tid * 8]);
    #pragma unroll
    for (int q = 0; q < 4; ++q)
      gl16(Bg + (size_t)(q * 32) * K + k0, &Bb[buf][q * 2048 + tid * 8]);
  };
  auto compute = [&](int buf) {
    const u16* Ac = Ab[buf];
    const u16* Bc = Bb[buf];
    short8v af[4], bf[4];
    #pragma unroll
    for (int ks = 0; ks < 2; ++ks) {
      const int co = ks ? co1 : co0;
      #pragma unroll
      for (int i = 0; i < 4; ++i) af[i] = *(const short8v*)&Ac[abase + i * 1024 + co];
      #pragma unroll
      for (int j = 0; j < 4; ++j) bf[j] = *(const short8v*)&Bc[bbase + j * 1024 + co];
      __builtin_amdgcn_s_setprio(1);
      #pragma unroll
      for (int i = 0; i < 4; ++i)
        #pragma unroll
        for (int j = 0; j < 4; ++j)
          acc[i][j] = __builtin_amdgcn_mfma_f32_16x16x32_bf16(af[i], bf[j], acc[i][j], 0, 0, 0);
      __builtin_amdgcn_s_setprio(0);
    }
  };

  // prologue: 2 tiles in flight (16 gl16/thread)
  issue(0, 0); issue(1, 1);
  #pragma unroll 1
  for (int t = 0; t < NT; ++t) {
    if (t + 1 < NT) asm volatile("s_waitcnt vmcnt(8)" ::: "memory");  // tile t landed
    else            asm volatile("s_waitcnt vmcnt(0)" ::: "memory");
    __builtin_amdgcn_s_barrier(); __builtin_amdgcn_sched_barrier(0);
    compute(t & 1);
    __builtin_amdgcn_s_barrier(); __builtin_amdgcn_sched_barrier(0);
    if (t + 2 < NT) issue(t + 2, t & 1);            // reuse buf just read
  }

  // epilogue: C row = (lane>>4)*4 + r, col = lane&15 (m89 mapping)
  const bool left = (bn < split);
  const int cb = bn - (left ? 0 : split) + wn * 64 + l15;
  const int rb = bm + wm * 64 + lq * 4;
  if (OBF16) {
    u16* Cp = (u16*)(left ? C0v : C1v);
    #pragma unroll
    for (int i = 0; i < 4; ++i)
      #pragma unroll
      for (int j = 0; j < 4; ++j)
        #pragma unroll
        for (int r = 0; r < 4; ++r)
          Cp[(size_t)(rb + i * 16 + r) * ldc + cb + j * 16] = f2bf(acc[i][j][r]);
  } else {
    float* Cp = (float*)(left ? C0v : C1v);
    #pragma unroll
    for (int i = 0; i < 4; ++i)
      #pragma unroll
      for (int j = 0; j < 4; ++j)
        #pragma unroll
        for (int r = 0; r < 4; ++r)
          Cp[(size_t)(rb + i * 16 + r) * ldc + cb + j * 16] = acc[i][j][r];
  }
}

// ---------------- skinny GEMM: xp_part[gy] = u @ W_x (K-slice) -------------
__global__ __launch_bounds__(256) void xp_gemm(
    const u16* __restrict__ A, const u16* __restrict__ Bt, float* __restrict__ xpp)
{
  __shared__ __align__(16) u16 Asm[128 * 32];
  __shared__ __align__(16) u16 Bsm[32 * 32];
  const int tid = threadIdx.x, lane = tid & 63, w = tid >> 6;
  const int bm = blockIdx.x * 128;
  const int kbase = blockIdx.y * (DI / KS);
  f32x4 acc[2][2] = {};
  const int srow = w * 32 + (lane >> 2);
  const int soct = lane & 3;
  const u16* Ap = A + (size_t)(bm + srow) * DI + kbase + soct * 8;
  const u16* Bp = Bt + (size_t)(lane >> 2) * DI + kbase + soct * 8;
  u16* As0 = &Asm[w * 1024];

  for (int k0 = 0; k0 < DI / KS; k0 += 32) {
    gl16(Ap + k0,                      As0);
    gl16(Ap + k0 + (size_t)16 * DI,    As0 + 512);
    if (w == 0) {
      gl16(Bp + k0,                    Bsm);
      gl16(Bp + k0 + (size_t)16 * DI,  Bsm + 512);
    }
    __syncthreads();
    short8v af[2], bf[2];
    #pragma unroll
    for (int i = 0; i < 2; ++i)
      af[i] = *(const short8v*)&Asm[(w * 32 + i * 16 + (lane & 15)) * 32 + (lane >> 4) * 8];
    #pragma unroll
    for (int j = 0; j < 2; ++j)
      bf[j] = *(const short8v*)&Bsm[(j * 16 + (lane & 15)) * 32 + (lane >> 4) * 8];
    #pragma unroll
    for (int i = 0; i < 2; ++i)
      #pragma unroll
      for (int j = 0; j < 2; ++j)
        acc[i][j] = __builtin_amdgcn_mfma_f32_16x16x32_bf16(af[i], bf[j], acc[i][j], 0, 0, 0);
    __syncthreads();
  }
  float* op = xpp + (size_t)blockIdx.y * NTOK * 32;
  const int rb = bm + w * 32 + (lane >> 4) * 4;
  const int cb = lane & 15;
  #pragma unroll
  for (int i = 0; i < 2; ++i)
    #pragma unroll
    for (int j = 0; j < 2; ++j)
      #pragma unroll
      for (int r = 0; r < 4; ++r)
        op[(size_t)(rb + i * 16 + r) * 32 + cb + j * 16] = acc[i][j][r];
}

// ------- dt/ub GEMM with fused K-split reduce (r14): xppart -> A-tile ------
// A = reduce_k xppart[k][.][.] -> bf16 (in-kernel, replaces xp_reduce);
// Bt = Wbig bf16 [4096][32]. cols < DI: dt = clip(softplus(acc + b_dt));
// else: ub = u * acc.
__global__ __launch_bounds__(256) void dtub_gemm(
    const float* __restrict__ xpp, const u16* __restrict__ Bt,
    const float* __restrict__ b_dt, const u16* __restrict__ u,
    u16* __restrict__ dt_out, u16* __restrict__ ub_out)
{
  __shared__ __align__(16) u16 Asm[128 * 32];
  __shared__ __align__(16) u16 Bsm[128 * 32];
  const int tid = threadIdx.x, lane = tid & 63, w = tid >> 6;
  const int wm = w >> 1, wn = w & 1;
  const int bm = blockIdx.y * 128, bn = blockIdx.x * 128;
  const int srow = w * 32 + (lane >> 2);
  const int soct = lane & 3;
  u16* Bs0 = &Bsm[w * 1024];
  gl16(Bt + (size_t)(bn + srow) * 32 + soct * 8,       Bs0);
  gl16(Bt + (size_t)(bn + srow) * 32 + soct * 8 + 512, Bs0 + 512);

  // A-tile: reduce the KS fp32 partials for rows [bm, bm+128), pack bf16
  {
    const int arow = tid >> 1;             // 0..127
    const int ach  = (tid & 1) * 16;       // col 0 or 16
    float s[16];
    #pragma unroll
    for (int e = 0; e < 16; ++e) s[e] = 0.f;
    const float* xp0 = xpp + (size_t)(bm + arow) * 32 + ach;
    #pragma unroll
    for (int k = 0; k < KS; ++k) {
      const float4* p = (const float4*)(xp0 + (size_t)k * NTOK * 32);
      #pragma unroll
      for (int q = 0; q < 4; ++q) {
        float4 v = p[q];
        s[q*4+0] += v.x; s[q*4+1] += v.y; s[q*4+2] += v.z; s[q*4+3] += v.w;
      }
    }
    u32 pk[8];
    #pragma unroll
    for (int q = 0; q < 8; ++q) pk[q] = pack2(s[2*q], s[2*q+1]);
    *(uint4*)&Asm[arow * 32 + ach]     = make_uint4(pk[0], pk[1], pk[2], pk[3]);
    *(uint4*)&Asm[arow * 32 + ach + 8] = make_uint4(pk[4], pk[5], pk[6], pk[7]);
  }
  __syncthreads();
  f32x4 acc[4][4] = {};
  short8v afr[4], bfr[4];
  #pragma unroll
  for (int i = 0; i < 4; ++i) {
    afr[i] = *(const short8v*)&Asm[(wm * 64 + i * 16 + (lane & 15)) * 32 + (lane >> 4) * 8];
    bfr[i] = *(const short8v*)&Bsm[(wn * 64 + i * 16 + (lane & 15)) * 32 + (lane >> 4) * 8];
  }
  #pragma unroll
  for (int i = 0; i < 4; ++i)
    #pragma unroll
    for (int j = 0; j < 4; ++j)
      acc[i][j] = __builtin_amdgcn_mfma_f32_16x16x32_bf16(afr[i], bfr[j], acc[i][j], 0, 0, 0);

  const int rb = bm + wm * 64 + (lane >> 4) * 4;
  const int cb = bn + wn * 64 + (lane & 15);
  if (bn < DI) {          // dt half
    float bd[4];
    #pragma unroll
    for (int j = 0; j < 4; ++j) bd[j] = b_dt[cb + j * 16];
    #pragma unroll
    for (int i = 0; i < 4; ++i)
      #pragma unroll
      for (int j = 0; j < 4; ++j)
        #pragma unroll
        for (int r = 0; r < 4; ++r) {
          float sp = softplus_f(acc[i][j][r] + bd[j]);
          sp = fminf(fmaxf(sp, 1e-4f), 1.0f);
          dt_out[(size_t)(rb + i * 16 + r) * DI + cb + j * 16] = f2bf(sp);
        }
  } else {                // ub half
    const int cn = cb - DI;
    #pragma unroll
    for (int i = 0; i < 4; ++i)
      #pragma unroll
      for (int j = 0; j < 4; ++j)
        #pragma unroll
        for (int r = 0; r < 4; ++r) {
          size_t off = (size_t)(rb + i * 16 + r) * DI + cn + j * 16;
          ub_out[off] = f2bf(b2f(u[off]) * acc[i][j][r]);
        }
  }
}

// ------- causal depthwise conv(4) + silu, bf16 io, 4 ch/thread -------------
__global__ __launch_bounds__(256) void conv_silu_k(
    const u16* __restrict__ xc, const float* __restrict__ cw, u16* __restrict__ u)
{
  int idx = blockIdx.x * 256 + threadIdx.x;   // over NTOK*DI/4
  int c = (idx & (DI / 4 - 1)) << 2;
  int r = idx >> 9;
  int t = r & (SEQ - 1);
  float4 w0 = ((const float4*)cw)[c + 0];
  float4 w1 = ((const float4*)cw)[c + 1];
  float4 w2 = ((const float4*)cw)[c + 2];
  float4 w3 = ((const float4*)cw)[c + 3];
  const u16* base = xc + (size_t)r * DI + c;
  uint2 v = *(const uint2*)base;
  float a0 = w0.w * lo2f(v.x), a1 = w1.w * hi2f(v.x);
  float a2 = w2.w * lo2f(v.y), a3 = w3.w * hi2f(v.y);
  if (t >= 1) { v = *(const uint2*)(base - DI);
    a0 += w0.z * lo2f(v.x); a1 += w1.z * hi2f(v.x); a2 += w2.z * lo2f(v.y); a3 += w3.z * hi2f(v.y); }
  if (t >= 2) { v = *(const uint2*)(base - 2 * DI);
    a0 += w0.y * lo2f(v.x); a1 += w1.y * hi2f(v.x); a2 += w2.y * lo2f(v.y); a3 += w3.y * hi2f(v.y); }
  if (t >= 3) { v = *(const uint2*)(base - 3 * DI);
    a0 += w0.x * lo2f(v.x); a1 += w1.x * hi2f(v.x); a2 += w2.x * lo2f(v.y); a3 += w3.x * hi2f(v.y); }
  *(uint2*)(u + (size_t)r * DI + c) =
      make_uint2(pack2(silu_f(a0), silu_f(a1)), pack2(silu_f(a2), silu_f(a3)));
}

// ---------------- chunked parallel scan (bf16 in, 4 ch/thread) -------------
__global__ __launch_bounds__(256) void scan_p1(
    const u16* __restrict__ dt_, const u16* __restrict__ ub,
    float* __restrict__ P, float* __restrict__ S)
{
  int idx = blockIdx.x * 256 + threadIdx.x;   // NB*CCH*DI/4
  int di = (idx & (DI / 4 - 1)) << 2;
  int bc = idx >> 9;
  int c  = bc & (CCH - 1);
  int b  = bc >> 5;
  size_t base = ((size_t)b * SEQ + (size_t)c * LC) * DI + di;
  float p0 = 1.f, s0 = 0.f, p1 = 1.f, s1 = 0.f;
  float p2 = 1.f, s2 = 0.f, p3 = 1.f, s3 = 0.f;
  #pragma unroll 4
  for (int t = 0; t < LC; ++t) {
    size_t off = base + (size_t)t * DI;
    uint2 dv = *(const uint2*)(dt_ + off);
    uint2 uv = *(const uint2*)(ub + off);
    float a0 = 1.f - lo2f(dv.x), a1 = 1.f - hi2f(dv.x);
    float a2 = 1.f - lo2f(dv.y), a3 = 1.f - hi2f(dv.y);
    s0 = s0 * a0 + lo2f(uv.x); p0 *= a0;
    s1 = s1 * a1 + hi2f(uv.x); p1 *= a1;
    s2 = s2 * a2 + lo2f(uv.y); p2 *= a2;
    s3 = s3 * a3 + hi2f(uv.y); p3 *= a3;
  }
  ((float4*)P)[idx] = make_float4(p0, p1, p2, p3);
  ((float4*)S)[idx] = make_float4(s0, s1, s2, s3);
}

__global__ __launch_bounds__(256) void scan_p2(
    const float* __restrict__ P, const float* __restrict__ S, float* __restrict__ Hin)
{
  int idx = blockIdx.x * 256 + threadIdx.x;   // NB*DI
  int di = idx & (DI - 1);
  int b  = idx >> 11;
  float h = 0.f;
  #pragma unroll
  for (int c = 0; c < CCH; ++c) {
    size_t off = ((size_t)b * CCH + c) * DI + di;
    Hin[off] = h;
    h = h * P[off] + S[off];
  }
}

// y bf16 in-place over dt (same-index read-before-write) — no __restrict__.
__global__ __launch_bounds__(256) void scan_p3(
    const u16* dt_, const u16* __restrict__ ub, const u16* __restrict__ u,
    const u16* __restrict__ z, const float* __restrict__ Dp_,
    const float* __restrict__ Hin, u16* y)
{
  int idx = blockIdx.x * 256 + threadIdx.x;   // NB*CCH*DI/4
  int di = (idx & (DI / 4 - 1)) << 2;
  int bc = idx >> 9;
  int c  = bc & (CCH - 1);
  int b  = bc >> 5;
  float4 dp = ((const float4*)Dp_)[di >> 2];
  float4 h4 = ((const float4*)Hin)[idx];
  float h0 = h4.x, h1 = h4.y, h2 = h4.z, h3 = h4.w;
  size_t base = ((size_t)b * SEQ + (size_t)c * LC) * DI + di;
  #pragma unroll 4
  for (int t = 0; t < LC; ++t) {
    size_t off = base + (size_t)t * DI;
    uint2 dv = *(const uint2*)(dt_ + off);
    uint2 uv = *(const uint2*)(ub + off);
    uint2 uu = *(const uint2*)(u + off);
    uint2 zv = *(const uint2*)(z + off);
    h0 = h0 * (1.f - lo2f(dv.x)) + lo2f(uv.x);
    h1 = h1 * (1.f - hi2f(dv.x)) + hi2f(uv.x);
    h2 = h2 * (1.f - lo2f(dv.y)) + lo2f(uv.y);
    h3 = h3 * (1.f - hi2f(dv.y)) + hi2f(uv.y);
    float y0 = (h0 + dp.x * lo2f(uu.x)) * silu_f(lo2f(zv.x));
    float y1 = (h1 + dp.y * hi2f(uu.x)) * silu_f(hi2f(zv.x));
    float y2 = (h2 + dp.z * lo2f(uu.y)) * silu_f(lo2f(zv.y));
    float y3 = (h3 + dp.w * hi2f(uu.y)) * silu_f(hi2f(zv.y));
    *(uint2*)(y + off) = make_uint2(pack2(y0, y1), pack2(y2, y3));
  }
}

extern "C" void kernel_launch(void* const* d_in, const int* in_sizes, int n_in,
                              void* d_out, int out_size, void* d_ws, size_t ws_size,
                              hipStream_t stream)
{
  const float* x     = (const float*)d_in[0];
  const float* W_in  = (const float*)d_in[1];
  const float* cw    = (const float*)d_in[2];
  const float* W_x   = (const float*)d_in[3];
  const float* W_dt  = (const float*)d_in[4];
  const float* b_dt  = (const float*)d_in[5];
  const float* W_Bp  = (const float*)d_in[6];
  const float* Dp    = (const float*)d_in[7];
  const float* W_out = (const float*)d_in[8];
  float* out = (float*)d_out;

  const size_t SZ = (size_t)NTOK * DI;        // floats per ws region
  float* w    = (float*)d_ws;
  float* bufA = w;
  float* bufB = w + SZ;
  float* bufC = w + 2 * SZ;
  float* bufD = w + 3 * SZ;

  u16* xcb  = (u16*)bufA;                     // xc bf16 -> dt bf16 -> y bf16
  u16* zb   = (u16*)bufB;                     // z bf16 [NTOK][DI]
  u16* wtob = zb + (size_t)NTOK * DI;         // Wt_out bf16 [DM][DI]
  u16* wxt  = wtob + (size_t)DM * DI;         // Wxt bf16 [32][DI]
  u16* wbig = wxt + (size_t)32 * DI;          // Wbig bf16 [4096][32]
  u16* xbf  = (u16*)bufC;                     // x bf16 [NTOK][DM]
  u16* wtib = xbf + (size_t)NTOK * DM;        // Wt_in bf16 [2DI][DM]
  u16* ubf  = (u16*)bufC;                     // u bf16 (over dead xbf/wtib)
  u16* ubb  = (u16*)bufD;                     // ub bf16

  const size_t PS = (size_t)NB * CCH * DI;    // 262144 floats
  float* Pbuf   = out;                        // scan + xp scratch in d_out
  float* Sbuf   = out + PS;                   // (GEMM2 rewrites d_out fully)
  float* Hin    = out + 2 * PS;
  float* xppart = out + 3 * PS;               // [KS][NTOK][32] fp32 (8 MB)
  (void)ws_size; (void)in_sizes; (void)n_in; (void)out_size;

  // 0) one-shot conversions / weight prep
  cvtk<<<(NTOK * DM / 4) / 256, 256, 0, stream>>>((const float4*)x, xbf, NTOK * DM / 4);
  transcvt<<<dim3((2 * DI) / 64, DM / 64), 256, 0, stream>>>(W_in, wtib, DM, 2 * DI);
  transcvt<<<dim3(DM / 64, DI / 64), 256, 0, stream>>>(W_out, wtob, DI, DM);
  prep_smallw<<<(32 * DI + 2 * DI * 32) / 256, 256, 0, stream>>>(W_x, W_dt, W_Bp, wxt, wbig);

  // 1) xz = x @ W_in -> xc (bf16, bufA), z (bf16, bufB)  [r11 2-resident]
  gemm2b<DM / 64, 1><<<dim3((2 * DI) / 128, NTOK / 128), 256, 0, stream>>>(
      xbf, wtib, (void*)xcb, (void*)zb, DM, DI, DI);

  // 2) u = silu(causal depthwise conv(xc))
  conv_silu_k<<<(NTOK * DI / 4) / 256, 256, 0, stream>>>(xcb, cw, ubf);

  // 3) xp partials = u @ W_x (K-split MFMA); dtub fuses the reduce (r14)
  xp_gemm<<<dim3(NTOK / 128, KS), 256, 0, stream>>>(ubf, wxt, xppart);
  dtub_gemm<<<dim3((2 * DI) / 128, NTOK / 128), 256, 0, stream>>>(
      xppart, wbig, b_dt, ubf, xcb, ubb);

  // 4) chunked scan + epilogue -> y bf16 (in place over dt)
  scan_p1<<<(NB * CCH * DI / 4) / 256, 256, 0, stream>>>(xcb, ubb, Pbuf, Sbuf);
  scan_p2<<<(NB * DI) / 256, 256, 0, stream>>>(Pbuf, Sbuf, Hin);
  scan_p3<<<(NB * CCH * DI / 4) / 256, 256, 0, stream>>>(xcb, ubb, ubf, zb, Dp, Hin, xcb);

  // 5) out = y @ W_out (fp32 out)  [r11 2-resident]
  gemm2b<DI / 64, 0><<<dim3(DM / 128, NTOK / 128), 256, 0, stream>>>(
      xcb, wtob, (void*)out, (void*)out, DI, DM, DM);
}

// Round 15
// 293.001 us; speedup vs baseline: 1.0535x; 1.0517x over previous
//
#include <hip/hip_runtime.h>
#include <cstdint>
#include <cstddef>

#define DM   1024
#define DI   2048
#define SEQ  2048
#define NB   4
#define NTOK (NB*SEQ)   // 8192
#define CCH  32          // scan chunks per sequence
#define LC   (SEQ/CCH)   // 64 timesteps per chunk
#define KS   8           // K-split for xp_gemm

typedef __attribute__((ext_vector_type(8))) short short8v;
typedef __attribute__((ext_vector_type(4))) float f32x4;
typedef unsigned short u16;
typedef unsigned int   u32;

__device__ __forceinline__ float silu_f(float x){ return x / (1.f + __expf(-x)); }

// cheap softplus: inline v_exp + v_log (log1pf is a slow libm path — r7 lesson)
__device__ __forceinline__ float softplus_f(float x){
  return (x > 20.f) ? x : __logf(1.f + __expf(x));
}

__device__ __forceinline__ u16 f2bf(float f){
  union { float f; u32 u; } c; c.f = f;
  u32 u = c.u + 0x7FFFu + ((c.u >> 16) & 1u);   // RNE
  return (u16)(u >> 16);
}
__device__ __forceinline__ float b2f(u16 b){
  union { u32 u; float f; } c; c.u = ((u32)b) << 16; return c.f;
}
__device__ __forceinline__ float lo2f(u32 v){ union { u32 u; float f; } c; c.u = v << 16; return c.f; }
__device__ __forceinline__ float hi2f(u32 v){ union { u32 u; float f; } c; c.u = v & 0xFFFF0000u; return c.f; }
__device__ __forceinline__ u32 pack2(float a, float b){ return (u32)f2bf(a) | ((u32)f2bf(b) << 16); }

__device__ __forceinline__ void gl16(const void* g, void* l){
  __builtin_amdgcn_global_load_lds((const __attribute__((address_space(1))) void*)g,
                                   (__attribute__((address_space(3))) void*)l, 16, 0, 0);
}

// ---------------- fused one-shot prep (r15): 4 launches -> 1 ---------------
// block-id ranges: [0,8192) cvtk; [8192,9216) transcvt W_in;
// [9216,9728) transcvt W_out; [9728,10496) prep_smallw.
#define PREP_CVT   8192
#define PREP_T1    (PREP_CVT + 1024)    // W_in:  bx 64 x by 16
#define PREP_T2    (PREP_T1 + 512)      // W_out: bx 16 x by 32
#define PREP_TOTAL (PREP_T2 + 768)

__device__ void transcvt_dev(const float* __restrict__ W, u16* __restrict__ Wt,
                             int R, int Cn, int bx, int by, int tid,
                             float (*t)[65])
{
  const int lr4 = tid >> 6;   // 0..3
  const int lc  = tid & 63;
  #pragma unroll
  for (int p = 0; p < 16; ++p) {
    int lr = p * 4 + lr4;
    t[lr][lc] = W[(size_t)(by * 64 + lr) * Cn + bx * 64 + lc];
  }
  __syncthreads();
  #pragma unroll
  for (int p = 0; p < 16; ++p) {
    int orr = p * 4 + lr4;
    Wt[(size_t)(bx * 64 + orr) * R + by * 64 + lc] = f2bf(t[lc][orr]);
  }
}

__global__ __launch_bounds__(256) void prep_all(
    const float* __restrict__ x, u16* __restrict__ xbf,
    const float* __restrict__ W_in, u16* __restrict__ wtib,
    const float* __restrict__ W_out, u16* __restrict__ wtob,
    const float* __restrict__ W_x, const float* __restrict__ W_dt,
    const float* __restrict__ W_Bp, u16* __restrict__ Wxt, u16* __restrict__ Wbig)
{
  __shared__ float t[64][65];
  const int bid = blockIdx.x, tid = threadIdx.x;
  if (bid < PREP_CVT) {
    int i = bid * 256 + tid;            // over NTOK*DM/4 float4s
    float4 v = ((const float4*)x)[i];
    *(uint2*)(xbf + (size_t)i * 4) = make_uint2(pack2(v.x, v.y), pack2(v.z, v.w));
  } else if (bid < PREP_T1) {
    int r = bid - PREP_CVT;             // W_in [DM][2DI] -> wtib [2DI][DM]
    transcvt_dev(W_in, wtib, DM, 2 * DI, r & 63, r >> 6, tid, t);
  } else if (bid < PREP_T2) {
    int r = bid - PREP_T1;              // W_out [DI][DM] -> wtob [DM][DI]
    transcvt_dev(W_out, wtob, DI, DM, r & 15, r >> 4, tid, t);
  } else {
    int i = (bid - PREP_T2) * 256 + tid;
    if (i < 32 * DI) {
      int j = i >> 11, c = i & (DI - 1);
      Wxt[i] = f2bf(W_x[c * 32 + j]);
    }
    int i2 = i - 32 * DI;
    if (i2 >= 0 && i2 < 2 * DI * 32) {
      int n = i2 >> 5, k = i2 & 31;
      float v;
      if (n < DI) v = (k < 16) ? W_dt[k * DI + n] : 0.f;
      else        v = (k >= 16) ? W_Bp[(k - 16) * DI + (n - DI)] : 0.f;
      Wbig[i2] = f2bf(v);
    }
  }
}

// ---------------- 2-resident-block pipelined MFMA GEMM (r11 config) --------
// A [M][K] bf16, Bt [N][K] bf16. BM=BN=128, BK=64, 256 thr (2x2 waves,
// 64x64/wave). 2-deep LDS dbuf = 64 KiB -> 2 blocks/CU (r11: cross-block
// TLP is what hides vmcnt/barrier stalls; r12 XCD-swizzle, r13 BK=32, and
// r8-r10 1-resident deep pipelines all regressed vs this — measured local
// optimum ~810 TF; m248 says 848 TF is the K=1024 full-stack reference).
// Counted vmcnt(8) (T4), XOR swizzle via pre-swizzled global source
// (rule #21, conflicts=0), setprio (T5).
template<int NT, int OBF16>
__global__ __launch_bounds__(256, 2) void gemm2b(
    const u16* __restrict__ A, const u16* __restrict__ Bt,
    void* C0v, void* C1v, int K, int split, int ldc)
{
  __shared__ __align__(16) u16 Ab[2][128 * 64];   // 2 x 16 KiB
  __shared__ __align__(16) u16 Bb[2][128 * 64];   // 2 x 16 KiB
  const int tid = threadIdx.x, lane = tid & 63, w = tid >> 6;
  const int wm = w >> 1, wn = w & 1;
  const int bm = blockIdx.y * 128, bn = blockIdx.x * 128;

  const int srow8 = tid >> 3;                     // 0..31
  const int kc = ((tid & 7) ^ (srow8 & 7)) << 3;  // swizzled u16 col
  const u16* Ag = A  + (size_t)(bm + srow8) * K + kc;
  const u16* Bg = Bt + (size_t)(bn + srow8) * K + kc;

  const int lq = lane >> 4, l15 = lane & 15;
  const int co0 = ((lq    ) ^ (l15 & 7)) << 3;    // ks=0 col (u16)
  const int co1 = ((lq + 4) ^ (l15 & 7)) << 3;    // ks=1
  const int abase = (wm * 64 + l15) * 64;
  const int bbase = (wn * 64 + l15) * 64;

  f32x4 acc[4][4] = {};

  auto issue = [&](int t, int buf) {
    const size_t k0 = (size_t)t << 6;
    #pragma unroll
    for (int q = 0; q < 4; ++q)
      gl16(Ag + (size_t)(q * 32) * K + k0, &Ab[buf][q * 2048 + tid * 8]);
    #pragma unroll
    for (int q = 0; q < 4; ++q)
      gl16(Bg + (size_t)(q * 32) * K + k0, &Bb[buf][q * 2048 + tid * 8]);
  };
  auto compute = [&](int buf) {
    const u16* Ac = Ab[buf];
    const u16* Bc = Bb[buf];
    short8v af[4], bf[4];
    #pragma unroll
    for (int ks = 0; ks < 2; ++ks) {
      const int co = ks ? co1 : co0;
      #pragma unroll
      for (int i = 0; i < 4; ++i) af[i] = *(const short8v*)&Ac[abase + i * 1024 + co];
      #pragma unroll
      for (int j = 0; j < 4; ++j) bf[j] = *(const short8v*)&Bc[bbase + j * 1024 + co];
      __builtin_amdgcn_s_setprio(1);
      #pragma unroll
      for (int i = 0; i < 4; ++i)
        #pragma unroll
        for (int j = 0; j < 4; ++j)
          acc[i][j] = __builtin_amdgcn_mfma_f32_16x16x32_bf16(af[i], bf[j], acc[i][j], 0, 0, 0);
      __builtin_amdgcn_s_setprio(0);
    }
  };

  issue(0, 0); issue(1, 1);
  #pragma unroll 1
  for (int t = 0; t < NT; ++t) {
    if (t + 1 < NT) asm volatile("s_waitcnt vmcnt(8)" ::: "memory");
    else            asm volatile("s_waitcnt vmcnt(0)" ::: "memory");
    __builtin_amdgcn_s_barrier(); __builtin_amdgcn_sched_barrier(0);
    compute(t & 1);
    __builtin_amdgcn_s_barrier(); __builtin_amdgcn_sched_barrier(0);
    if (t + 2 < NT) issue(t + 2, t & 1);
  }

  // epilogue: C row = (lane>>4)*4 + r, col = lane&15 (m89 mapping)
  const bool left = (bn < split);
  const int cb = bn - (left ? 0 : split) + wn * 64 + l15;
  const int rb = bm + wm * 64 + lq * 4;
  if (OBF16) {
    u16* Cp = (u16*)(left ? C0v : C1v);
    #pragma unroll
    for (int i = 0; i < 4; ++i)
      #pragma unroll
      for (int j = 0; j < 4; ++j)
        #pragma unroll
        for (int r = 0; r < 4; ++r)
          Cp[(size_t)(rb + i * 16 + r) * ldc + cb + j * 16] = f2bf(acc[i][j][r]);
  } else {
    float* Cp = (float*)(left ? C0v : C1v);
    #pragma unroll
    for (int i = 0; i < 4; ++i)
      #pragma unroll
      for (int j = 0; j < 4; ++j)
        #pragma unroll
        for (int r = 0; r < 4; ++r)
          Cp[(size_t)(rb + i * 16 + r) * ldc + cb + j * 16] = acc[i][j][r];
  }
}

// ---------------- skinny GEMM: xp_part[gy] = u @ W_x (K-slice) -------------
__global__ __launch_bounds__(256) void xp_gemm(
    const u16* __restrict__ A, const u16* __restrict__ Bt, float* __restrict__ xpp)
{
  __shared__ __align__(16) u16 Asm[128 * 32];
  __shared__ __align__(16) u16 Bsm[32 * 32];
  const int tid = threadIdx.x, lane = tid & 63, w = tid >> 6;
  const int bm = blockIdx.x * 128;
  const int kbase = blockIdx.y * (DI / KS);
  f32x4 acc[2][2] = {};
  const int srow = w * 32 + (lane >> 2);
  const int soct = lane & 3;
  const u16* Ap = A + (size_t)(bm + srow) * DI + kbase + soct * 8;
  const u16* Bp = Bt + (size_t)(lane >> 2) * DI + kbase + soct * 8;
  u16* As0 = &Asm[w * 1024];

  for (int k0 = 0; k0 < DI / KS; k0 += 32) {
    gl16(Ap + k0,                      As0);
    gl16(Ap + k0 + (size_t)16 * DI,    As0 + 512);
    if (w == 0) {
      gl16(Bp + k0,                    Bsm);
      gl16(Bp + k0 + (size_t)16 * DI,  Bsm + 512);
    }
    __syncthreads();
    short8v af[2], bf[2];
    #pragma unroll
    for (int i = 0; i < 2; ++i)
      af[i] = *(const short8v*)&Asm[(w * 32 + i * 16 + (lane & 15)) * 32 + (lane >> 4) * 8];
    #pragma unroll
    for (int j = 0; j < 2; ++j)
      bf[j] = *(const short8v*)&Bsm[(j * 16 + (lane & 15)) * 32 + (lane >> 4) * 8];
    #pragma unroll
    for (int i = 0; i < 2; ++i)
      #pragma unroll
      for (int j = 0; j < 2; ++j)
        acc[i][j] = __builtin_amdgcn_mfma_f32_16x16x32_bf16(af[i], bf[j], acc[i][j], 0, 0, 0);
    __syncthreads();
  }
  float* op = xpp + (size_t)blockIdx.y * NTOK * 32;
  const int rb = bm + w * 32 + (lane >> 4) * 4;
  const int cb = lane & 15;
  #pragma unroll
  for (int i = 0; i < 2; ++i)
    #pragma unroll
    for (int j = 0; j < 2; ++j)
      #pragma unroll
      for (int r = 0; r < 4; ++r)
        op[(size_t)(rb + i * 16 + r) * 32 + cb + j * 16] = acc[i][j][r];
}

// ---------------- reduce KS partials -> xp bf16 ----------------------------
__global__ __launch_bounds__(256) void xp_reduce(
    const float* __restrict__ xpp, u16* __restrict__ xpb)
{
  int i = blockIdx.x * 256 + threadIdx.x;   // over NTOK*32
  float s = 0.f;
  #pragma unroll
  for (int k = 0; k < KS; ++k) s += xpp[(size_t)k * NTOK * 32 + i];
  xpb[i] = f2bf(s);
}

// ---------------- dt/ub GEMM: [xp][Wbig] K=32, fused epilogue (r11) --------
__global__ __launch_bounds__(256) void dtub_gemm(
    const u16* __restrict__ A, const u16* __restrict__ Bt,
    const float* __restrict__ b_dt, const u16* __restrict__ u,
    u16* __restrict__ dt_out, u16* __restrict__ ub_out)
{
  __shared__ __align__(16) u16 Asm[128 * 32];
  __shared__ __align__(16) u16 Bsm[128 * 32];
  const int tid = threadIdx.x, lane = tid & 63, w = tid >> 6;
  const int wm = w >> 1, wn = w & 1;
  const int bm = blockIdx.y * 128, bn = blockIdx.x * 128;
  const int srow = w * 32 + (lane >> 2);
  const int soct = lane & 3;
  u16* As0 = &Asm[w * 1024];
  u16* Bs0 = &Bsm[w * 1024];
  gl16(A  + (size_t)(bm + srow) * 32 + soct * 8,       As0);
  gl16(A  + (size_t)(bm + srow) * 32 + soct * 8 + 512, As0 + 512);
  gl16(Bt + (size_t)(bn + srow) * 32 + soct * 8,       Bs0);
  gl16(Bt + (size_t)(bn + srow) * 32 + soct * 8 + 512, Bs0 + 512);
  __syncthreads();
  f32x4 acc[4][4] = {};
  short8v afr[4], bfr[4];
  #pragma unroll
  for (int i = 0; i < 4; ++i) {
    afr[i] = *(const short8v*)&Asm[(wm * 64 + i * 16 + (lane & 15)) * 32 + (lane >> 4) * 8];
    bfr[i] = *(const short8v*)&Bsm[(wn * 64 + i * 16 + (lane & 15)) * 32 + (lane >> 4) * 8];
  }
  #pragma unroll
  for (int i = 0; i < 4; ++i)
    #pragma unroll
    for (int j = 0; j < 4; ++j)
      acc[i][j] = __builtin_amdgcn_mfma_f32_16x16x32_bf16(afr[i], bfr[j], acc[i][j], 0, 0, 0);

  const int rb = bm + wm * 64 + (lane >> 4) * 4;
  const int cb = bn + wn * 64 + (lane & 15);
  if (bn < DI) {          // dt half
    float bd[4];
    #pragma unroll
    for (int j = 0; j < 4; ++j) bd[j] = b_dt[cb + j * 16];
    #pragma unroll
    for (int i = 0; i < 4; ++i)
      #pragma unroll
      for (int j = 0; j < 4; ++j)
        #pragma unroll
        for (int r = 0; r < 4; ++r) {
          float sp = softplus_f(acc[i][j][r] + bd[j]);
          sp = fminf(fmaxf(sp, 1e-4f), 1.0f);
          dt_out[(size_t)(rb + i * 16 + r) * DI + cb + j * 16] = f2bf(sp);
        }
  } else {                // ub half
    const int cn = cb - DI;
    #pragma unroll
    for (int i = 0; i < 4; ++i)
      #pragma unroll
      for (int j = 0; j < 4; ++j)
        #pragma unroll
        for (int r = 0; r < 4; ++r) {
          size_t off = (size_t)(rb + i * 16 + r) * DI + cn + j * 16;
          ub_out[off] = f2bf(b2f(u[off]) * acc[i][j][r]);
        }
  }
}

// ------- causal depthwise conv(4) + silu, bf16 io, 4 ch/thread -------------
__global__ __launch_bounds__(256) void conv_silu_k(
    const u16* __restrict__ xc, const float* __restrict__ cw, u16* __restrict__ u)
{
  int idx = blockIdx.x * 256 + threadIdx.x;   // over NTOK*DI/4
  int c = (idx & (DI / 4 - 1)) << 2;
  int r = idx >> 9;
  int t = r & (SEQ - 1);
  float4 w0 = ((const float4*)cw)[c + 0];
  float4 w1 = ((const float4*)cw)[c + 1];
  float4 w2 = ((const float4*)cw)[c + 2];
  float4 w3 = ((const float4*)cw)[c + 3];
  const u16* base = xc + (size_t)r * DI + c;
  uint2 v = *(const uint2*)base;
  float a0 = w0.w * lo2f(v.x), a1 = w1.w * hi2f(v.x);
  float a2 = w2.w * lo2f(v.y), a3 = w3.w * hi2f(v.y);
  if (t >= 1) { v = *(const uint2*)(base - DI);
    a0 += w0.z * lo2f(v.x); a1 += w1.z * hi2f(v.x); a2 += w2.z * lo2f(v.y); a3 += w3.z * hi2f(v.y); }
  if (t >= 2) { v = *(const uint2*)(base - 2 * DI);
    a0 += w0.y * lo2f(v.x); a1 += w1.y * hi2f(v.x); a2 += w2.y * lo2f(v.y); a3 += w3.y * hi2f(v.y); }
  if (t >= 3) { v = *(const uint2*)(base - 3 * DI);
    a0 += w0.x * lo2f(v.x); a1 += w1.x * hi2f(v.x); a2 += w2.x * lo2f(v.y); a3 += w3.x * hi2f(v.y); }
  *(uint2*)(u + (size_t)r * DI + c) =
      make_uint2(pack2(silu_f(a0), silu_f(a1)), pack2(silu_f(a2), silu_f(a3)));
}

// ---------------- chunked parallel scan (bf16 in, 4 ch/thread) -------------
__global__ __launch_bounds__(256) void scan_p1(
    const u16* __restrict__ dt_, const u16* __restrict__ ub,
    float* __restrict__ P, float* __restrict__ S)
{
  int idx = blockIdx.x * 256 + threadIdx.x;   // NB*CCH*DI/4
  int di = (idx & (DI / 4 - 1)) << 2;
  int bc = idx >> 9;
  int c  = bc & (CCH - 1);
  int b  = bc >> 5;
  size_t base = ((size_t)b * SEQ + (size_t)c * LC) * DI + di;
  float p0 = 1.f, s0 = 0.f, p1 = 1.f, s1 = 0.f;
  float p2 = 1.f, s2 = 0.f, p3 = 1.f, s3 = 0.f;
  #pragma unroll 4
  for (int t = 0; t < LC; ++t) {
    size_t off = base + (size_t)t * DI;
    uint2 dv = *(const uint2*)(dt_ + off);
    uint2 uv = *(const uint2*)(ub + off);
    float a0 = 1.f - lo2f(dv.x), a1 = 1.f - hi2f(dv.x);
    float a2 = 1.f - lo2f(dv.y), a3 = 1.f - hi2f(dv.y);
    s0 = s0 * a0 + lo2f(uv.x); p0 *= a0;
    s1 = s1 * a1 + hi2f(uv.x); p1 *= a1;
    s2 = s2 * a2 + lo2f(uv.y); p2 *= a2;
    s3 = s3 * a3 + hi2f(uv.y); p3 *= a3;
  }
  ((float4*)P)[idx] = make_float4(p0, p1, p2, p3);
  ((float4*)S)[idx] = make_float4(s0, s1, s2, s3);
}

__global__ __launch_bounds__(256) void scan_p2(
    const float* __restrict__ P, const float* __restrict__ S, float* __restrict__ Hin)
{
  int idx = blockIdx.x * 256 + threadIdx.x;   // NB*DI
  int di = idx & (DI - 1);
  int b  = idx >> 11;
  float h = 0.f;
  #pragma unroll
  for (int c = 0; c < CCH; ++c) {
    size_t off = ((size_t)b * CCH + c) * DI + di;
    Hin[off] = h;
    h = h * P[off] + S[off];
  }
}

// y bf16 in-place over dt (same-index read-before-write) — no __restrict__.
__global__ __launch_bounds__(256) void scan_p3(
    const u16* dt_, const u16* __restrict__ ub, const u16* __restrict__ u,
    const u16* __restrict__ z, const float* __restrict__ Dp_,
    const float* __restrict__ Hin, u16* y)
{
  int idx = blockIdx.x * 256 + threadIdx.x;   // NB*CCH*DI/4
  int di = (idx & (DI / 4 - 1)) << 2;
  int bc = idx >> 9;
  int c  = bc & (CCH - 1);
  int b  = bc >> 5;
  float4 dp = ((const float4*)Dp_)[di >> 2];
  float4 h4 = ((const float4*)Hin)[idx];
  float h0 = h4.x, h1 = h4.y, h2 = h4.z, h3 = h4.w;
  size_t base = ((size_t)b * SEQ + (size_t)c * LC) * DI + di;
  #pragma unroll 4
  for (int t = 0; t < LC; ++t) {
    size_t off = base + (size_t)t * DI;
    uint2 dv = *(const uint2*)(dt_ + off);
    uint2 uv = *(const uint2*)(ub + off);
    uint2 uu = *(const uint2*)(u + off);
    uint2 zv = *(const uint2*)(z + off);
    h0 = h0 * (1.f - lo2f(dv.x)) + lo2f(uv.x);
    h1 = h1 * (1.f - hi2f(dv.x)) + hi2f(uv.x);
    h2 = h2 * (1.f - lo2f(dv.y)) + lo2f(uv.y);
    h3 = h3 * (1.f - hi2f(dv.y)) + hi2f(uv.y);
    float y0 = (h0 + dp.x * lo2f(uu.x)) * silu_f(lo2f(zv.x));
    float y1 = (h1 + dp.y * hi2f(uu.x)) * silu_f(hi2f(zv.x));
    float y2 = (h2 + dp.z * lo2f(uu.y)) * silu_f(lo2f(zv.y));
    float y3 = (h3 + dp.w * hi2f(uu.y)) * silu_f(hi2f(zv.y));
    *(uint2*)(y + off) = make_uint2(pack2(y0, y1), pack2(y2, y3));
  }
}

extern "C" void kernel_launch(void* const* d_in, const int* in_sizes, int n_in,
                              void* d_out, int out_size, void* d_ws, size_t ws_size,
                              hipStream_t stream)
{
  const float* x     = (const float*)d_in[0];
  const float* W_in  = (const float*)d_in[1];
  const float* cw    = (const float*)d_in[2];
  const float* W_x   = (const float*)d_in[3];
  const float* W_dt  = (const float*)d_in[4];
  const float* b_dt  = (const float*)d_in[5];
  const float* W_Bp  = (const float*)d_in[6];
  const float* Dp    = (const float*)d_in[7];
  const float* W_out = (const float*)d_in[8];
  float* out = (float*)d_out;

  const size_t SZ = (size_t)NTOK * DI;        // floats per ws region
  float* w    = (float*)d_ws;
  float* bufA = w;
  float* bufB = w + SZ;
  float* bufC = w + 2 * SZ;
  float* bufD = w + 3 * SZ;

  u16* xcb  = (u16*)bufA;                     // xc bf16 -> dt bf16 -> y bf16
  u16* zb   = (u16*)bufB;                     // z bf16 [NTOK][DI]
  u16* wtob = zb + (size_t)NTOK * DI;         // Wt_out bf16 [DM][DI]
  u16* wxt  = wtob + (size_t)DM * DI;         // Wxt bf16 [32][DI]
  u16* wbig = wxt + (size_t)32 * DI;          // Wbig bf16 [4096][32]
  u16* xbf  = (u16*)bufC;                     // x bf16 [NTOK][DM]
  u16* wtib = xbf + (size_t)NTOK * DM;        // Wt_in bf16 [2DI][DM]
  u16* ubf  = (u16*)bufC;                     // u bf16 (over dead xbf/wtib)
  u16* ubb  = (u16*)bufD;                     // ub bf16

  const size_t PS = (size_t)NB * CCH * DI;    // 262144 floats
  float* Pbuf   = out;                        // scan + xp scratch in d_out
  float* Sbuf   = out + PS;                   // (GEMM2 rewrites d_out fully)
  float* Hin    = out + 2 * PS;
  float* xppart = out + 3 * PS;               // [KS][NTOK][32] fp32 (8 MB)
  u16*   xpb    = (u16*)(out + 3 * PS + (size_t)KS * NTOK * 32);
  (void)ws_size; (void)in_sizes; (void)n_in; (void)out_size;

  // 0) fused one-shot conversions / weight prep (r15: 4 launches -> 1)
  prep_all<<<PREP_TOTAL, 256, 0, stream>>>(
      x, xbf, W_in, wtib, W_out, wtob, W_x, W_dt, W_Bp, wxt, wbig);

  // 1) xz = x @ W_in -> xc (bf16, bufA), z (bf16, bufB)  [r11 2-resident]
  gemm2b<DM / 64, 1><<<dim3((2 * DI) / 128, NTOK / 128), 256, 0, stream>>>(
      xbf, wtib, (void*)xcb, (void*)zb, DM, DI, DI);

  // 2) u = silu(causal depthwise conv(xc))
  conv_silu_k<<<(NTOK * DI / 4) / 256, 256, 0, stream>>>(xcb, cw, ubf);

  // 3) xp = u @ W_x (K-split MFMA + separate reduce — r14 fusion reverted:
  //    in-dtub reduce re-read partials 32x = 256 MB extra traffic)
  xp_gemm<<<dim3(NTOK / 128, KS), 256, 0, stream>>>(ubf, wxt, xppart);
  xp_reduce<<<(NTOK * 32) / 256, 256, 0, stream>>>(xppart, xpb);
  dtub_gemm<<<dim3((2 * DI) / 128, NTOK / 128), 256, 0, stream>>>(
      xpb, wbig, b_dt, ubf, xcb, ubb);

  // 4) chunked scan + epilogue -> y bf16 (in place over dt)
  scan_p1<<<(NB * CCH * DI / 4) / 256, 256, 0, stream>>>(xcb, ubb, Pbuf, Sbuf);
  scan_p2<<<(NB * DI) / 256, 256, 0, stream>>>(Pbuf, Sbuf, Hin);
  scan_p3<<<(NB * CCH * DI / 4) / 256, 256, 0, stream>>>(xcb, ubb, ubf, zb, Dp, Hin, xcb);

  // 5) out = y @ W_out (fp32 out)  [r11 2-resident]
  gemm2b<DI / 64, 0><<<dim3(DM / 128, NTOK / 128), 256, 0, stream>>>(
      xcb, wtob, (void*)out, (void*)out, DI, DM, DM);
}

// Round 16
// 281.012 us; speedup vs baseline: 1.0984x; 1.0427x over previous
//
#include <hip/hip_runtime.h>
#include <cstdint>
#include <cstddef>

#define DM   1024
#define DI   2048
#define SEQ  2048
#define NB   4
#define NTOK (NB*SEQ)   // 8192
#define CCH  32          // scan chunks per sequence
#define LC   (SEQ/CCH)   // 64 timesteps per chunk
#define KS   8           // K-split for xp_gemm

typedef __attribute__((ext_vector_type(8))) short short8v;
typedef __attribute__((ext_vector_type(4))) float f32x4;
typedef unsigned short u16;
typedef unsigned int   u32;

__device__ __forceinline__ float silu_f(float x){ return x / (1.f + __expf(-x)); }

// cheap softplus: inline v_exp + v_log (log1pf is a slow libm path — r7 lesson)
__device__ __forceinline__ float softplus_f(float x){
  return (x > 20.f) ? x : __logf(1.f + __expf(x));
}

__device__ __forceinline__ u16 f2bf(float f){
  union { float f; u32 u; } c; c.f = f;
  u32 u = c.u + 0x7FFFu + ((c.u >> 16) & 1u);   // RNE
  return (u16)(u >> 16);
}
__device__ __forceinline__ float b2f(u16 b){
  union { u32 u; float f; } c; c.u = ((u32)b) << 16; return c.f;
}
__device__ __forceinline__ float lo2f(u32 v){ union { u32 u; float f; } c; c.u = v << 16; return c.f; }
__device__ __forceinline__ float hi2f(u32 v){ union { u32 u; float f; } c; c.u = v & 0xFFFF0000u; return c.f; }
__device__ __forceinline__ u32 pack2(float a, float b){ return (u32)f2bf(a) | ((u32)f2bf(b) << 16); }

__device__ __forceinline__ void gl16(const void* g, void* l){
  __builtin_amdgcn_global_load_lds((const __attribute__((address_space(1))) void*)g,
                                   (__attribute__((address_space(3))) void*)l, 16, 0, 0);
}

// ---------------- fused one-shot prep: 4 launches -> 1 ---------------------
#define PREP_CVT   8192
#define PREP_T1    (PREP_CVT + 1024)    // W_in:  bx 64 x by 16
#define PREP_T2    (PREP_T1 + 512)      // W_out: bx 16 x by 32
#define PREP_TOTAL (PREP_T2 + 768)

__device__ void transcvt_dev(const float* __restrict__ W, u16* __restrict__ Wt,
                             int R, int Cn, int bx, int by, int tid,
                             float (*t)[65])
{
  const int lr4 = tid >> 6;   // 0..3
  const int lc  = tid & 63;
  #pragma unroll
  for (int p = 0; p < 16; ++p) {
    int lr = p * 4 + lr4;
    t[lr][lc] = W[(size_t)(by * 64 + lr) * Cn + bx * 64 + lc];
  }
  __syncthreads();
  #pragma unroll
  for (int p = 0; p < 16; ++p) {
    int orr = p * 4 + lr4;
    Wt[(size_t)(bx * 64 + orr) * R + by * 64 + lc] = f2bf(t[lc][orr]);
  }
}

__global__ __launch_bounds__(256) void prep_all(
    const float* __restrict__ x, u16* __restrict__ xbf,
    const float* __restrict__ W_in, u16* __restrict__ wtib,
    const float* __restrict__ W_out, u16* __restrict__ wtob,
    const float* __restrict__ W_x, const float* __restrict__ W_dt,
    const float* __restrict__ W_Bp, u16* __restrict__ Wxt, u16* __restrict__ Wbig)
{
  __shared__ float t[64][65];
  const int bid = blockIdx.x, tid = threadIdx.x;
  if (bid < PREP_CVT) {
    int i = bid * 256 + tid;            // over NTOK*DM/4 float4s
    float4 v = ((const float4*)x)[i];
    *(uint2*)(xbf + (size_t)i * 4) = make_uint2(pack2(v.x, v.y), pack2(v.z, v.w));
  } else if (bid < PREP_T1) {
    int r = bid - PREP_CVT;             // W_in [DM][2DI] -> wtib [2DI][DM]
    transcvt_dev(W_in, wtib, DM, 2 * DI, r & 63, r >> 6, tid, t);
  } else if (bid < PREP_T2) {
    int r = bid - PREP_T1;              // W_out [DI][DM] -> wtob [DM][DI]
    transcvt_dev(W_out, wtob, DI, DM, r & 15, r >> 4, tid, t);
  } else {
    int i = (bid - PREP_T2) * 256 + tid;
    if (i < 32 * DI) {
      int j = i >> 11, c = i & (DI - 1);
      Wxt[i] = f2bf(W_x[c * 32 + j]);
    }
    int i2 = i - 32 * DI;
    if (i2 >= 0 && i2 < 2 * DI * 32) {
      int n = i2 >> 5, k = i2 & 31;
      float v;
      if (n < DI) v = (k < 16) ? W_dt[k * DI + n] : 0.f;
      else        v = (k >= 16) ? W_Bp[(k - 16) * DI + (n - DI)] : 0.f;
      Wbig[i2] = f2bf(v);
    }
  }
}

// ---------------- 2-resident-block pipelined MFMA GEMM (r11 config) --------
// Measured local optimum ~810 TF (r11); r8-r10 deep pipelines, r12 XCD
// swizzle, r13 BK=32 all regressed. Counted vmcnt(8) (T4), XOR swizzle via
// pre-swizzled global source (rule #21, conflicts=0), setprio (T5).
template<int NT, int OBF16>
__global__ __launch_bounds__(256, 2) void gemm2b(
    const u16* __restrict__ A, const u16* __restrict__ Bt,
    void* C0v, void* C1v, int K, int split, int ldc)
{
  __shared__ __align__(16) u16 Ab[2][128 * 64];   // 2 x 16 KiB
  __shared__ __align__(16) u16 Bb[2][128 * 64];   // 2 x 16 KiB
  const int tid = threadIdx.x, lane = tid & 63, w = tid >> 6;
  const int wm = w >> 1, wn = w & 1;
  const int bm = blockIdx.y * 128, bn = blockIdx.x * 128;

  const int srow8 = tid >> 3;                     // 0..31
  const int kc = ((tid & 7) ^ (srow8 & 7)) << 3;  // swizzled u16 col
  const u16* Ag = A  + (size_t)(bm + srow8) * K + kc;
  const u16* Bg = Bt + (size_t)(bn + srow8) * K + kc;

  const int lq = lane >> 4, l15 = lane & 15;
  const int co0 = ((lq    ) ^ (l15 & 7)) << 3;    // ks=0 col (u16)
  const int co1 = ((lq + 4) ^ (l15 & 7)) << 3;    // ks=1
  const int abase = (wm * 64 + l15) * 64;
  const int bbase = (wn * 64 + l15) * 64;

  f32x4 acc[4][4] = {};

  auto issue = [&](int t, int buf) {
    const size_t k0 = (size_t)t << 6;
    #pragma unroll
    for (int q = 0; q < 4; ++q)
      gl16(Ag + (size_t)(q * 32) * K + k0, &Ab[buf][q * 2048 + tid * 8]);
    #pragma unroll
    for (int q = 0; q < 4; ++q)
      gl16(Bg + (size_t)(q * 32) * K + k0, &Bb[buf][q * 2048 + tid * 8]);
  };
  auto compute = [&](int buf) {
    const u16* Ac = Ab[buf];
    const u16* Bc = Bb[buf];
    short8v af[4], bf[4];
    #pragma unroll
    for (int ks = 0; ks < 2; ++ks) {
      const int co = ks ? co1 : co0;
      #pragma unroll
      for (int i = 0; i < 4; ++i) af[i] = *(const short8v*)&Ac[abase + i * 1024 + co];
      #pragma unroll
      for (int j = 0; j < 4; ++j) bf[j] = *(const short8v*)&Bc[bbase + j * 1024 + co];
      __builtin_amdgcn_s_setprio(1);
      #pragma unroll
      for (int i = 0; i < 4; ++i)
        #pragma unroll
        for (int j = 0; j < 4; ++j)
          acc[i][j] = __builtin_amdgcn_mfma_f32_16x16x32_bf16(af[i], bf[j], acc[i][j], 0, 0, 0);
      __builtin_amdgcn_s_setprio(0);
    }
  };

  issue(0, 0); issue(1, 1);
  #pragma unroll 1
  for (int t = 0; t < NT; ++t) {
    if (t + 1 < NT) asm volatile("s_waitcnt vmcnt(8)" ::: "memory");
    else            asm volatile("s_waitcnt vmcnt(0)" ::: "memory");
    __builtin_amdgcn_s_barrier(); __builtin_amdgcn_sched_barrier(0);
    compute(t & 1);
    __builtin_amdgcn_s_barrier(); __builtin_amdgcn_sched_barrier(0);
    if (t + 2 < NT) issue(t + 2, t & 1);
  }

  // epilogue: C row = (lane>>4)*4 + r, col = lane&15 (m89 mapping)
  const bool left = (bn < split);
  const int cb = bn - (left ? 0 : split) + wn * 64 + l15;
  const int rb = bm + wm * 64 + lq * 4;
  if (OBF16) {
    u16* Cp = (u16*)(left ? C0v : C1v);
    #pragma unroll
    for (int i = 0; i < 4; ++i)
      #pragma unroll
      for (int j = 0; j < 4; ++j)
        #pragma unroll
        for (int r = 0; r < 4; ++r)
          Cp[(size_t)(rb + i * 16 + r) * ldc + cb + j * 16] = f2bf(acc[i][j][r]);
  } else {
    float* Cp = (float*)(left ? C0v : C1v);
    #pragma unroll
    for (int i = 0; i < 4; ++i)
      #pragma unroll
      for (int j = 0; j < 4; ++j)
        #pragma unroll
        for (int r = 0; r < 4; ++r)
          Cp[(size_t)(rb + i * 16 + r) * ldc + cb + j * 16] = acc[i][j][r];
  }
}

// ---------------- skinny GEMM: xp_part[gy] = u @ W_x (K-slice) -------------
__global__ __launch_bounds__(256) void xp_gemm(
    const u16* __restrict__ A, const u16* __restrict__ Bt, float* __restrict__ xpp)
{
  __shared__ __align__(16) u16 Asm[128 * 32];
  __shared__ __align__(16) u16 Bsm[32 * 32];
  const int tid = threadIdx.x, lane = tid & 63, w = tid >> 6;
  const int bm = blockIdx.x * 128;
  const int kbase = blockIdx.y * (DI / KS);
  f32x4 acc[2][2] = {};
  const int srow = w * 32 + (lane >> 2);
  const int soct = lane & 3;
  const u16* Ap = A + (size_t)(bm + srow) * DI + kbase + soct * 8;
  const u16* Bp = Bt + (size_t)(lane >> 2) * DI + kbase + soct * 8;
  u16* As0 = &Asm[w * 1024];

  for (int k0 = 0; k0 < DI / KS; k0 += 32) {
    gl16(Ap + k0,                      As0);
    gl16(Ap + k0 + (size_t)16 * DI,    As0 + 512);
    if (w == 0) {
      gl16(Bp + k0,                    Bsm);
      gl16(Bp + k0 + (size_t)16 * DI,  Bsm + 512);
    }
    __syncthreads();
    short8v af[2], bf[2];
    #pragma unroll
    for (int i = 0; i < 2; ++i)
      af[i] = *(const short8v*)&Asm[(w * 32 + i * 16 + (lane & 15)) * 32 + (lane >> 4) * 8];
    #pragma unroll
    for (int j = 0; j < 2; ++j)
      bf[j] = *(const short8v*)&Bsm[(j * 16 + (lane & 15)) * 32 + (lane >> 4) * 8];
    #pragma unroll
    for (int i = 0; i < 2; ++i)
      #pragma unroll
      for (int j = 0; j < 2; ++j)
        acc[i][j] = __builtin_amdgcn_mfma_f32_16x16x32_bf16(af[i], bf[j], acc[i][j], 0, 0, 0);
    __syncthreads();
  }
  float* op = xpp + (size_t)blockIdx.y * NTOK * 32;
  const int rb = bm + w * 32 + (lane >> 4) * 4;
  const int cb = lane & 15;
  #pragma unroll
  for (int i = 0; i < 2; ++i)
    #pragma unroll
    for (int j = 0; j < 2; ++j)
      #pragma unroll
      for (int r = 0; r < 4; ++r)
        op[(size_t)(rb + i * 16 + r) * 32 + cb + j * 16] = acc[i][j][r];
}

// ---------------- reduce KS partials -> xp bf16 ----------------------------
__global__ __launch_bounds__(256) void xp_reduce(
    const float* __restrict__ xpp, u16* __restrict__ xpb)
{
  int i = blockIdx.x * 256 + threadIdx.x;   // over NTOK*32
  float s = 0.f;
  #pragma unroll
  for (int k = 0; k < KS; ++k) s += xpp[(size_t)k * NTOK * 32 + i];
  xpb[i] = f2bf(s);
}

// ------- dt/ub GEMM + fused chunk-scan (r16) -------------------------------
// Each block now computes BOTH halves (dt AND ub) for channels [bc,bc+128)
// over tokens [bm,bm+128) = exactly 2 scan chunks. After the MFMA epilogue
// the dt/ub tile round-trips through unioned LDS (Asm/Bsm dead) and each
// thread runs one (chunk, channel) 64-step scan -> P/S. Eliminates
// scan_p1's 64 MB global re-read. Scan reads same post-f2bf bf16 values
// scan_p1 read -> numerically identical. Grid: (DI/128, NTOK/128).
__global__ __launch_bounds__(256) void dtub_scan(
    const u16* __restrict__ A,      // xp bf16 [NTOK][32]
    const u16* __restrict__ Bt,     // Wbig bf16 [4096][32]
    const float* __restrict__ b_dt, const u16* __restrict__ u,
    u16* __restrict__ dt_out, u16* __restrict__ ub_out,
    float* __restrict__ P, float* __restrict__ S)
{
  __shared__ __align__(16) u16 smem[32768];   // 64 KiB unioned
  u16* Asm = smem;                 // [128*32]  (MFMA phase)
  u16* Bsm = smem + 4096;          // [2][128*32]
  const int tid = threadIdx.x, lane = tid & 63, w = tid >> 6;
  const int wm = w >> 1, wn = w & 1;
  const int bm = blockIdx.y * 128, bc = blockIdx.x * 128;
  const int srow = w * 32 + (lane >> 2);
  const int soct = lane & 3;
  u16* As0 = Asm + w * 1024;
  u16* Bs0 = Bsm + w * 1024;            // dt weights
  u16* Bs1 = Bsm + 4096 + w * 1024;     // ub (Bp) weights
  gl16(A  + (size_t)(bm + srow) * 32 + soct * 8,            As0);
  gl16(A  + (size_t)(bm + srow) * 32 + soct * 8 + 512,      As0 + 512);
  gl16(Bt + (size_t)(bc + srow) * 32 + soct * 8,            Bs0);
  gl16(Bt + (size_t)(bc + srow) * 32 + soct * 8 + 512,      Bs0 + 512);
  gl16(Bt + (size_t)(DI + bc + srow) * 32 + soct * 8,       Bs1);
  gl16(Bt + (size_t)(DI + bc + srow) * 32 + soct * 8 + 512, Bs1 + 512);
  __syncthreads();

  const int lq = lane >> 4, l15 = lane & 15;
  f32x4 accd[4][4] = {}, accu[4][4] = {};
  short8v afr[4], bfd[4], bfu[4];
  #pragma unroll
  for (int i = 0; i < 4; ++i) {
    afr[i] = *(const short8v*)&Asm[(wm * 64 + i * 16 + l15) * 32 + lq * 8];
    bfd[i] = *(const short8v*)&Bsm[(wn * 64 + i * 16 + l15) * 32 + lq * 8];
    bfu[i] = *(const short8v*)&Bsm[4096 + (wn * 64 + i * 16 + l15) * 32 + lq * 8];
  }
  #pragma unroll
  for (int i = 0; i < 4; ++i)
    #pragma unroll
    for (int j = 0; j < 4; ++j) {
      accd[i][j] = __builtin_amdgcn_mfma_f32_16x16x32_bf16(afr[i], bfd[j], accd[i][j], 0, 0, 0);
      accu[i][j] = __builtin_amdgcn_mfma_f32_16x16x32_bf16(afr[i], bfu[j], accu[i][j], 0, 0, 0);
    }
  __syncthreads();                       // Asm/Bsm dead -> reuse for scan tiles
  u16* dtL = smem;                       // [128][128] bf16
  u16* ubL = smem + 16384;

  // epilogue: local row = wm*64 + lq*4 + i*16 + r, local col = wn*64+l15+j*16
  const int rl = wm * 64 + lq * 4;
  const int cl = wn * 64 + l15;
  float bd[4];
  #pragma unroll
  for (int j = 0; j < 4; ++j) bd[j] = b_dt[bc + cl + j * 16];
  #pragma unroll
  for (int i = 0; i < 4; ++i)
    #pragma unroll
    for (int j = 0; j < 4; ++j)
      #pragma unroll
      for (int r = 0; r < 4; ++r) {
        const int row = rl + i * 16 + r, col = cl + j * 16;
        const size_t off = (size_t)(bm + row) * DI + bc + col;
        float sp = softplus_f(accd[i][j][r] + bd[j]);
        sp = fminf(fmaxf(sp, 1e-4f), 1.0f);
        u16 dv = f2bf(sp);
        u16 uv = f2bf(b2f(u[off]) * accu[i][j][r]);
        dt_out[off] = dv; dtL[row * 128 + col] = dv;
        ub_out[off] = uv; ubL[row * 128 + col] = uv;
      }
  __syncthreads();

  // in-block chunk scan: thread -> (chunk = tid>>7, ch = tid&127)
  {
    const int chunk = tid >> 7, ch = tid & 127;
    float p = 1.f, s = 0.f;
    #pragma unroll 4
    for (int t = 0; t < LC; ++t) {
      int rr = chunk * LC + t;
      float a = 1.f - b2f(dtL[rr * 128 + ch]);
      s = s * a + b2f(ubL[rr * 128 + ch]);
      p *= a;
    }
    const int gt = (bm >> 6) + chunk;    // global chunk id (= b*CCH + c)
    P[(size_t)gt * DI + bc + ch] = p;
    S[(size_t)gt * DI + bc + ch] = s;
  }
}

// ------- causal depthwise conv(4) + silu, bf16 io, 4 ch/thread -------------
__global__ __launch_bounds__(256) void conv_silu_k(
    const u16* __restrict__ xc, const float* __restrict__ cw, u16* __restrict__ u)
{
  int idx = blockIdx.x * 256 + threadIdx.x;   // over NTOK*DI/4
  int c = (idx & (DI / 4 - 1)) << 2;
  int r = idx >> 9;
  int t = r & (SEQ - 1);
  float4 w0 = ((const float4*)cw)[c + 0];
  float4 w1 = ((const float4*)cw)[c + 1];
  float4 w2 = ((const float4*)cw)[c + 2];
  float4 w3 = ((const float4*)cw)[c + 3];
  const u16* base = xc + (size_t)r * DI + c;
  uint2 v = *(const uint2*)base;
  float a0 = w0.w * lo2f(v.x), a1 = w1.w * hi2f(v.x);
  float a2 = w2.w * lo2f(v.y), a3 = w3.w * hi2f(v.y);
  if (t >= 1) { v = *(const uint2*)(base - DI);
    a0 += w0.z * lo2f(v.x); a1 += w1.z * hi2f(v.x); a2 += w2.z * lo2f(v.y); a3 += w3.z * hi2f(v.y); }
  if (t >= 2) { v = *(const uint2*)(base - 2 * DI);
    a0 += w0.y * lo2f(v.x); a1 += w1.y * hi2f(v.x); a2 += w2.y * lo2f(v.y); a3 += w3.y * hi2f(v.y); }
  if (t >= 3) { v = *(const uint2*)(base - 3 * DI);
    a0 += w0.x * lo2f(v.x); a1 += w1.x * hi2f(v.x); a2 += w2.x * lo2f(v.y); a3 += w3.x * hi2f(v.y); }
  *(uint2*)(u + (size_t)r * DI + c) =
      make_uint2(pack2(silu_f(a0), silu_f(a1)), pack2(silu_f(a2), silu_f(a3)));
}

// ---------------- chunk compose + final scan (unchanged) -------------------
__global__ __launch_bounds__(256) void scan_p2(
    const float* __restrict__ P, const float* __restrict__ S, float* __restrict__ Hin)
{
  int idx = blockIdx.x * 256 + threadIdx.x;   // NB*DI
  int di = idx & (DI - 1);
  int b  = idx >> 11;
  float h = 0.f;
  #pragma unroll
  for (int c = 0; c < CCH; ++c) {
    size_t off = ((size_t)b * CCH + c) * DI + di;
    Hin[off] = h;
    h = h * P[off] + S[off];
  }
}

// y bf16 in-place over dt (same-index read-before-write) — no __restrict__.
__global__ __launch_bounds__(256) void scan_p3(
    const u16* dt_, const u16* __restrict__ ub, const u16* __restrict__ u,
    const u16* __restrict__ z, const float* __restrict__ Dp_,
    const float* __restrict__ Hin, u16* y)
{
  int idx = blockIdx.x * 256 + threadIdx.x;   // NB*CCH*DI/4
  int di = (idx & (DI / 4 - 1)) << 2;
  int bc = idx >> 9;
  int c  = bc & (CCH - 1);
  int b  = bc >> 5;
  float4 dp = ((const float4*)Dp_)[di >> 2];
  float4 h4 = ((const float4*)Hin)[idx];
  float h0 = h4.x, h1 = h4.y, h2 = h4.z, h3 = h4.w;
  size_t base = ((size_t)b * SEQ + (size_t)c * LC) * DI + di;
  #pragma unroll 4
  for (int t = 0; t < LC; ++t) {
    size_t off = base + (size_t)t * DI;
    uint2 dv = *(const uint2*)(dt_ + off);
    uint2 uv = *(const uint2*)(ub + off);
    uint2 uu = *(const uint2*)(u + off);
    uint2 zv = *(const uint2*)(z + off);
    h0 = h0 * (1.f - lo2f(dv.x)) + lo2f(uv.x);
    h1 = h1 * (1.f - hi2f(dv.x)) + hi2f(uv.x);
    h2 = h2 * (1.f - lo2f(dv.y)) + lo2f(uv.y);
    h3 = h3 * (1.f - hi2f(dv.y)) + hi2f(uv.y);
    float y0 = (h0 + dp.x * lo2f(uu.x)) * silu_f(lo2f(zv.x));
    float y1 = (h1 + dp.y * hi2f(uu.x)) * silu_f(hi2f(zv.x));
    float y2 = (h2 + dp.z * lo2f(uu.y)) * silu_f(lo2f(zv.y));
    float y3 = (h3 + dp.w * hi2f(uu.y)) * silu_f(hi2f(zv.y));
    *(uint2*)(y + off) = make_uint2(pack2(y0, y1), pack2(y2, y3));
  }
}

extern "C" void kernel_launch(void* const* d_in, const int* in_sizes, int n_in,
                              void* d_out, int out_size, void* d_ws, size_t ws_size,
                              hipStream_t stream)
{
  const float* x     = (const float*)d_in[0];
  const float* W_in  = (const float*)d_in[1];
  const float* cw    = (const float*)d_in[2];
  const float* W_x   = (const float*)d_in[3];
  const float* W_dt  = (const float*)d_in[4];
  const float* b_dt  = (const float*)d_in[5];
  const float* W_Bp  = (const float*)d_in[6];
  const float* Dp    = (const float*)d_in[7];
  const float* W_out = (const float*)d_in[8];
  float* out = (float*)d_out;

  const size_t SZ = (size_t)NTOK * DI;        // floats per ws region
  float* w    = (float*)d_ws;
  float* bufA = w;
  float* bufB = w + SZ;
  float* bufC = w + 2 * SZ;
  float* bufD = w + 3 * SZ;

  u16* xcb  = (u16*)bufA;                     // xc bf16 -> dt bf16 -> y bf16
  u16* zb   = (u16*)bufB;                     // z bf16 [NTOK][DI]
  u16* wtob = zb + (size_t)NTOK * DI;         // Wt_out bf16 [DM][DI]
  u16* wxt  = wtob + (size_t)DM * DI;         // Wxt bf16 [32][DI]
  u16* wbig = wxt + (size_t)32 * DI;          // Wbig bf16 [4096][32]
  u16* xbf  = (u16*)bufC;                     // x bf16 [NTOK][DM]
  u16* wtib = xbf + (size_t)NTOK * DM;        // Wt_in bf16 [2DI][DM]
  u16* ubf  = (u16*)bufC;                     // u bf16 (over dead xbf/wtib)
  u16* ubb  = (u16*)bufD;                     // ub bf16

  const size_t PS = (size_t)NB * CCH * DI;    // 262144 floats
  float* Pbuf   = out;                        // scan + xp scratch in d_out
  float* Sbuf   = out + PS;                   // (GEMM2 rewrites d_out fully)
  float* Hin    = out + 2 * PS;
  float* xppart = out + 3 * PS;               // [KS][NTOK][32] fp32 (8 MB)
  u16*   xpb    = (u16*)(out + 3 * PS + (size_t)KS * NTOK * 32);
  (void)ws_size; (void)in_sizes; (void)n_in; (void)out_size;

  // 0) fused one-shot conversions / weight prep
  prep_all<<<PREP_TOTAL, 256, 0, stream>>>(
      x, xbf, W_in, wtib, W_out, wtob, W_x, W_dt, W_Bp, wxt, wbig);

  // 1) xz = x @ W_in -> xc (bf16, bufA), z (bf16, bufB)  [r11 2-resident]
  gemm2b<DM / 64, 1><<<dim3((2 * DI) / 128, NTOK / 128), 256, 0, stream>>>(
      xbf, wtib, (void*)xcb, (void*)zb, DM, DI, DI);

  // 2) u = silu(causal depthwise conv(xc))
  conv_silu_k<<<(NTOK * DI / 4) / 256, 256, 0, stream>>>(xcb, cw, ubf);

  // 3) xp = u @ W_x (K-split MFMA + reduce); dt/ub GEMM + fused chunk-scan
  xp_gemm<<<dim3(NTOK / 128, KS), 256, 0, stream>>>(ubf, wxt, xppart);
  xp_reduce<<<(NTOK * 32) / 256, 256, 0, stream>>>(xppart, xpb);
  dtub_scan<<<dim3(DI / 128, NTOK / 128), 256, 0, stream>>>(
      xpb, wbig, b_dt, ubf, xcb, ubb, Pbuf, Sbuf);

  // 4) chunk compose + final scan + epilogue -> y bf16 (in place over dt)
  scan_p2<<<(NB * DI) / 256, 256, 0, stream>>>(Pbuf, Sbuf, Hin);
  scan_p3<<<(NB * CCH * DI / 4) / 256, 256, 0, stream>>>(xcb, ubb, ubf, zb, Dp, Hin, xcb);

  // 5) out = y @ W_out (fp32 out)  [r11 2-resident]
  gemm2b<DI / 64, 0><<<dim3(DM / 128, NTOK / 128), 256, 0, stream>>>(
      xcb, wtob, (void*)out, (void*)out, DI, DM, DM);
}